// Round 7
// baseline (11848.907 us; speedup 1.0000x reference)
//
#include <hip/hip_runtime.h>
#include <cstdint>
#include <cstddef>

#define NROWS 12288
#define FDIM 768
#define HDIM 512
#define ODIM 256
#define TOPK 31                // knn_k + 1
#define SPLITS 8
#define CPS (NROWS / SPLITS)   // 1536 columns per split

#define NEG_INF_F (-__builtin_inff())
#define IDX_MAX 0x7fffffff

// ---------------------------------------------------------------------------
// fp32 GEMM bitwise-matching OpenBLAS sgemm gemm_driver K-blocking:
//   min_l = k-ls; if (min_l >= 2Q) min_l = Q; else if (min_l > Q) min_l=(min_l+1)/2
// with Q=384. For K=768 -> panels [384,384]; K=512 -> [256,256]. Both are a
// single fold at K/2: panel chains are serial ascending-k FMA per element
// (SIMD lanes on M/N only); panel 2 folded into C with one fp32 add (beta=0
// first panel, then C += panel).
// C = A[M][K] * B[Nout][K]^T + bias (bias added as separate fp32 op).
// 64x64 tile, 256 threads, 4x4 micro-tile, BK=32.
// ---------------------------------------------------------------------------
template<bool RELU>
__global__ __launch_bounds__(256)
void gemm_nt_serial(const float* __restrict__ A, const float* __restrict__ B,
                    const float* __restrict__ bias, float* __restrict__ C,
                    int Nout, int K)
{
  __shared__ float As[32][68];
  __shared__ float Bs[32][68];
  const int tid = threadIdx.x;
  const int tx = tid & 15, ty = tid >> 4;
  const int r0 = blockIdx.y * 64, c0 = blockIdx.x * 64;
  float acc[4][4] = {};    // current panel chain
  float accC[4][4];        // folded C value (OpenBLAS C memory)
  bool first = true;
  const int Khalf = K / 2;

  for (int k0 = 0; k0 < K; k0 += 32) {
#pragma unroll
    for (int l = 0; l < 2; ++l) {
      const int lin = l * 256 + tid;
      const int row = lin >> 3, kq = lin & 7;
      const float4 a = *(const float4*)(A + (size_t)(r0 + row) * K + k0 + kq * 4);
      As[kq * 4 + 0][row] = a.x; As[kq * 4 + 1][row] = a.y;
      As[kq * 4 + 2][row] = a.z; As[kq * 4 + 3][row] = a.w;
      const float4 b = *(const float4*)(B + (size_t)(c0 + row) * K + k0 + kq * 4);
      Bs[kq * 4 + 0][row] = b.x; Bs[kq * 4 + 1][row] = b.y;
      Bs[kq * 4 + 2][row] = b.z; Bs[kq * 4 + 3][row] = b.w;
    }
    __syncthreads();
#pragma unroll
    for (int kk = 0; kk < 32; ++kk) {     // k strictly ascending within panel
      const float4 av = *(const float4*)&As[kk][ty * 4];
      const float4 bv = *(const float4*)&Bs[kk][tx * 4];
      const float a4[4] = {av.x, av.y, av.z, av.w};
      const float b4[4] = {bv.x, bv.y, bv.z, bv.w};
#pragma unroll
      for (int i = 0; i < 4; ++i)
#pragma unroll
        for (int j = 0; j < 4; ++j)
          acc[i][j] = fmaf(a4[i], b4[j], acc[i][j]);   // fused, matches BLAS
    }
    __syncthreads();

    // Panel boundary at K/2 and at K: fold panel chain into C
    if ((k0 + 32 == Khalf) || (k0 + 32 == K)) {
#pragma unroll
      for (int i = 0; i < 4; ++i)
#pragma unroll
        for (int j = 0; j < 4; ++j) {
          accC[i][j] = first ? acc[i][j] : __fadd_rn(accC[i][j], acc[i][j]);
          acc[i][j] = 0.f;
        }
      first = false;
    }
  }

  const float4 bq = *(const float4*)(bias + c0 + tx * 4);
  const float bb[4] = {bq.x, bq.y, bq.z, bq.w};
#pragma unroll
  for (int i = 0; i < 4; ++i) {
    float v[4];
#pragma unroll
    for (int j = 0; j < 4; ++j) {
      v[j] = __fadd_rn(accC[i][j], bb[j]);  // separate fp32 add (numpy "+ b")
      if (RELU) v[j] = fmaxf(v[j], 0.f);
    }
    float4 o; o.x = v[0]; o.y = v[1]; o.z = v[2]; o.w = v[3];
    *(float4*)(C + (size_t)(r0 + ty * 4 + i) * Nout + c0 + tx * 4) = o;
  }
}

// ---------------------------------------------------------------------------
// Row L2-normalize replicating numpy BITWISE for n=256:
//   pairwise_sum: n=256>128 -> pw(a,128) + pw(a+128,128); each 128-block via
//   the 8-accumulator loop; combine ((r0+r1)+(r2+r3))+((r4+r5)+(r6+r7)).
//   Squares rounded fp32 before summing; norm = IEEE sqrt (__fsqrt_rn);
//   d = max(norm, 1e-12); e = x/d in IEEE fp32 division (__fdiv_rn).
// One thread per row.
// ---------------------------------------------------------------------------
__global__ __launch_bounds__(256)
void l2norm_np(float* __restrict__ X)
{
  const int row = blockIdx.x * 256 + threadIdx.x;
  float* x = X + (size_t)row * ODIM;

  float S = 0.f;
#pragma unroll
  for (int h = 0; h < 2; ++h) {
    const float* a = x + h * 128;
    float r0 = __fmul_rn(a[0], a[0]);
    float r1 = __fmul_rn(a[1], a[1]);
    float r2 = __fmul_rn(a[2], a[2]);
    float r3 = __fmul_rn(a[3], a[3]);
    float r4 = __fmul_rn(a[4], a[4]);
    float r5 = __fmul_rn(a[5], a[5]);
    float r6 = __fmul_rn(a[6], a[6]);
    float r7 = __fmul_rn(a[7], a[7]);
    for (int i = 8; i < 128; i += 8) {
      r0 = __fadd_rn(r0, __fmul_rn(a[i + 0], a[i + 0]));
      r1 = __fadd_rn(r1, __fmul_rn(a[i + 1], a[i + 1]));
      r2 = __fadd_rn(r2, __fmul_rn(a[i + 2], a[i + 2]));
      r3 = __fadd_rn(r3, __fmul_rn(a[i + 3], a[i + 3]));
      r4 = __fadd_rn(r4, __fmul_rn(a[i + 4], a[i + 4]));
      r5 = __fadd_rn(r5, __fmul_rn(a[i + 5], a[i + 5]));
      r6 = __fadd_rn(r6, __fmul_rn(a[i + 6], a[i + 6]));
      r7 = __fadd_rn(r7, __fmul_rn(a[i + 7], a[i + 7]));
    }
    const float half = __fadd_rn(
        __fadd_rn(__fadd_rn(r0, r1), __fadd_rn(r2, r3)),
        __fadd_rn(__fadd_rn(r4, r5), __fadd_rn(r6, r7)));
    S = (h == 0) ? half : __fadd_rn(S, half);
  }

  const float d = fmaxf(__fsqrt_rn(S), 1e-12f);   // IEEE sqrt, matches np
  for (int k = 0; k < ODIM; ++k) x[k] = __fdiv_rn(x[k], d);
}

// ---------------------------------------------------------------------------
// fp32 sim = E @ E^T: K=256 <= Q=384 -> OpenBLAS uses a SINGLE serial-k FMA
// chain — matched here. Fused with EXACT per-row top-31 (sorted insertion,
// value desc / index asc). 32 rows x 64 cols per tile, 256 threads, 2x4
// micro-tile. Grid: (NROWS/32) * SPLITS.
// ---------------------------------------------------------------------------
__global__ __launch_bounds__(256)
void sim_topk(const float* __restrict__ E, float* __restrict__ lv,
              int* __restrict__ li)
{
  __shared__ float As[32][36];
  __shared__ float Bs[32][68];
  __shared__ float stile[32][65];
  __shared__ float tv[32][TOPK];
  __shared__ int   ti[32][TOPK];

  const int tid = threadIdx.x;
  const int tx = tid & 15, ty = tid >> 4;
  const int rb = blockIdx.x / SPLITS, sp = blockIdx.x % SPLITS;
  const int r0 = rb * 32, cbase = sp * CPS;

  if (tid < 32) {
#pragma unroll
    for (int s = 0; s < TOPK; ++s) { tv[tid][s] = NEG_INF_F; ti[tid][s] = IDX_MAX; }
  }
  __syncthreads();

  for (int t = 0; t < CPS / 64; ++t) {
    const int c0 = cbase + t * 64;
    float acc[2][4] = {};
#pragma unroll
    for (int k0 = 0; k0 < ODIM; k0 += 32) {
      {  // stage A: 32 rows x 32 k
        const int row = tid >> 3, kq = tid & 7;
        const float4 a = *(const float4*)(E + (size_t)(r0 + row) * ODIM + k0 + kq * 4);
        As[kq * 4 + 0][row] = a.x; As[kq * 4 + 1][row] = a.y;
        As[kq * 4 + 2][row] = a.z; As[kq * 4 + 3][row] = a.w;
      }
#pragma unroll
      for (int l = 0; l < 2; ++l) {  // stage B: 64 cols x 32 k
        const int lin = l * 256 + tid;
        const int col = lin >> 3, kq = lin & 7;
        const float4 b = *(const float4*)(E + (size_t)(c0 + col) * ODIM + k0 + kq * 4);
        Bs[kq * 4 + 0][col] = b.x; Bs[kq * 4 + 1][col] = b.y;
        Bs[kq * 4 + 2][col] = b.z; Bs[kq * 4 + 3][col] = b.w;
      }
      __syncthreads();
#pragma unroll
      for (int kk = 0; kk < 32; ++kk) {   // serial ascending k, single chain
        const float2 av = *(const float2*)&As[kk][ty * 2];
        const float4 bv = *(const float4*)&Bs[kk][tx * 4];
        const float a2[2] = {av.x, av.y};
        const float b4[4] = {bv.x, bv.y, bv.z, bv.w};
#pragma unroll
        for (int i = 0; i < 2; ++i)
#pragma unroll
          for (int j = 0; j < 4; ++j)
            acc[i][j] = fmaf(a2[i], b4[j], acc[i][j]);
      }
      __syncthreads();
    }
#pragma unroll
    for (int i = 0; i < 2; ++i)
#pragma unroll
      for (int j = 0; j < 4; ++j)
        stile[ty * 2 + i][tx * 4 + j] = acc[i][j];
    __syncthreads();
    if (tid < 32) {  // exact sorted-insertion scan; thread owns row tid
      for (int c = 0; c < 64; ++c) {
        const float v = stile[tid][c];
        const int gc = c0 + c;
        const float lastv = tv[tid][TOPK - 1];
        const int lasti = ti[tid][TOPK - 1];
        if (v > lastv || (v == lastv && gc < lasti)) {
          int p = TOPK - 1;
          while (p > 0) {
            const float pv = tv[tid][p - 1];
            const int pi = ti[tid][p - 1];
            if (!(v > pv || (v == pv && gc < pi))) break;
            tv[tid][p] = pv; ti[tid][p] = pi;
            --p;
          }
          tv[tid][p] = v; ti[tid][p] = gc;
        }
      }
    }
    __syncthreads();
  }

  if (tid < 32) {
    const int row = r0 + tid;
#pragma unroll
    for (int s = 0; s < TOPK; ++s) {
      lv[(size_t)(sp * TOPK + s) * NROWS + row] = tv[tid][s];
      li[(size_t)(sp * TOPK + s) * NROWS + row] = ti[tid][s];
    }
  }
}

// ---------------------------------------------------------------------------
// Exact 8-way merge of sorted split lists -> final top-31 pairs per row.
// ---------------------------------------------------------------------------
__global__ __launch_bounds__(64)
void merge31(const float* __restrict__ lv, const int* __restrict__ li,
             float* __restrict__ fv, int* __restrict__ fi)
{
  const int row = blockIdx.x * 64 + threadIdx.x;
  int pos[SPLITS] = {0, 0, 0, 0, 0, 0, 0, 0};
  for (int k = 0; k < TOPK; ++k) {
    float bv = NEG_INF_F; int bi = IDX_MAX; int bs = 0;
#pragma unroll
    for (int sp = 0; sp < SPLITS; ++sp) {
      const int p = pos[sp];                 // p <= k < TOPK, in range
      const float v = lv[(size_t)(sp * TOPK + p) * NROWS + row];
      const int ix = li[(size_t)(sp * TOPK + p) * NROWS + row];
      if (v > bv || (v == bv && ix < bi)) { bv = v; bi = ix; bs = sp; }
    }
    fv[(size_t)row * TOPK + k] = bv;
    fi[(size_t)row * TOPK + k] = bi;
    pos[bs] += 1;
  }
}

// ---------------------------------------------------------------------------
// Zero-fill output (grid-stride float4).
// ---------------------------------------------------------------------------
__global__ __launch_bounds__(256)
void zero_out(float4* __restrict__ out, size_t n4)
{
  size_t i = (size_t)blockIdx.x * blockDim.x + threadIdx.x;
  const size_t stride = (size_t)gridDim.x * blockDim.x;
  const float4 z = {0.f, 0.f, 0.f, 0.f};
  for (; i < n4; i += stride) out[i] = z;
}

// ---------------------------------------------------------------------------
// Scatter relu(final values) into zeroed output. One thread per row.
// ---------------------------------------------------------------------------
__global__ __launch_bounds__(64)
void scatter31(const float* __restrict__ fv, const int* __restrict__ fi,
               float* __restrict__ out)
{
  const int row = blockIdx.x * 64 + threadIdx.x;
  for (int k = 0; k < TOPK; ++k) {
    const int ix = fi[(size_t)row * TOPK + k];
    const float v = fv[(size_t)row * TOPK + k];
    out[(size_t)row * NROWS + ix] = fmaxf(v, 0.f);
  }
}

// ---------------------------------------------------------------------------
extern "C" void kernel_launch(void* const* d_in, const int* in_sizes, int n_in,
                              void* d_out, int out_size, void* d_ws, size_t ws_size,
                              hipStream_t stream)
{
  const float* feat = (const float*)d_in[0];
  const float* W1 = (const float*)d_in[1];
  const float* b1 = (const float*)d_in[2];
  const float* W2 = (const float*)d_in[3];
  const float* b2 = (const float*)d_in[4];
  const float* W3 = (const float*)d_in[5];
  const float* b3 = (const float*)d_in[6];
  float* out = (float*)d_out;

  // d_out as scratch (604 MB fp32), all consumed before zero_out:
  float* X1 = (float*)d_out;                                 // 25.2 MB
  float* X2 = X1 + (size_t)NROWS * HDIM;                     // 25.2 MB
  float* lv = (float*)((char*)d_out + (size_t)128 * 1024 * 1024);  // 12.2 MB
  int* li = (int*)(lv + (size_t)SPLITS * TOPK * NROWS);      // 12.2 MB
  // d_ws (15.6 MB): E + final pairs (survive zero_out)
  float* E = (float*)d_ws;                                   // 12.6 MB
  float* fv = E + (size_t)NROWS * ODIM;                      // 1.5 MB
  int* fi = (int*)(fv + (size_t)NROWS * TOPK);               // 1.5 MB

  gemm_nt_serial<true><<<dim3(HDIM / 64, NROWS / 64), 256, 0, stream>>>(
      feat, W1, b1, X1, HDIM, FDIM);
  gemm_nt_serial<true><<<dim3(HDIM / 64, NROWS / 64), 256, 0, stream>>>(
      X1, W2, b2, X2, HDIM, HDIM);
  gemm_nt_serial<false><<<dim3(ODIM / 64, NROWS / 64), 256, 0, stream>>>(
      X2, W3, b3, E, ODIM, HDIM);
  l2norm_np<<<NROWS / 256, 256, 0, stream>>>(E);
  sim_topk<<<(NROWS / 32) * SPLITS, 256, 0, stream>>>(E, lv, li);
  merge31<<<NROWS / 64, 64, 0, stream>>>(lv, li, fv, fi);
  zero_out<<<2048, 256, 0, stream>>>((float4*)out, (size_t)NROWS * NROWS / 4);
  scatter31<<<NROWS / 64, 64, 0, stream>>>(fv, fi, out);
}

// Round 8
// 10215.111 us; speedup vs baseline: 1.1599x; 1.1599x over previous
//
#include <hip/hip_runtime.h>
#include <cstdint>
#include <cstddef>

#define NROWS 12288
#define FDIM 768
#define HDIM 512
#define ODIM 256
#define TOPK 31                // knn_k + 1
#define SPLITS 8
#define CPS (NROWS / SPLITS)   // 1536 columns per split

#define NEG_INF_F (-__builtin_inff())
#define IDX_MAX 0x7fffffff

// ---------------------------------------------------------------------------
// fp32 GEMM bitwise-matching OpenBLAS sgemm gemm_driver K-blocking:
// panels [K/2,K/2] for K in {512,768} (Q=384 balanced split), serial
// ascending-k FMA chain per element within panel, one fp32 add to fold.
// C = A[M][K] * B[Nout][K]^T + bias. 64x64 tile, 256 thr, 4x4 micro, BK=32.
// ---------------------------------------------------------------------------
template<bool RELU>
__global__ __launch_bounds__(256)
void gemm_nt_serial(const float* __restrict__ A, const float* __restrict__ B,
                    const float* __restrict__ bias, float* __restrict__ C,
                    int Nout, int K)
{
  __shared__ float As[32][68];
  __shared__ float Bs[32][68];
  const int tid = threadIdx.x;
  const int tx = tid & 15, ty = tid >> 4;
  const int r0 = blockIdx.y * 64, c0 = blockIdx.x * 64;
  float acc[4][4] = {};    // current panel chain
  float accC[4][4];        // folded C value (OpenBLAS C memory)
  bool first = true;
  const int Khalf = K / 2;

  for (int k0 = 0; k0 < K; k0 += 32) {
#pragma unroll
    for (int l = 0; l < 2; ++l) {
      const int lin = l * 256 + tid;
      const int row = lin >> 3, kq = lin & 7;
      const float4 a = *(const float4*)(A + (size_t)(r0 + row) * K + k0 + kq * 4);
      As[kq * 4 + 0][row] = a.x; As[kq * 4 + 1][row] = a.y;
      As[kq * 4 + 2][row] = a.z; As[kq * 4 + 3][row] = a.w;
      const float4 b = *(const float4*)(B + (size_t)(c0 + row) * K + k0 + kq * 4);
      Bs[kq * 4 + 0][row] = b.x; Bs[kq * 4 + 1][row] = b.y;
      Bs[kq * 4 + 2][row] = b.z; Bs[kq * 4 + 3][row] = b.w;
    }
    __syncthreads();
#pragma unroll
    for (int kk = 0; kk < 32; ++kk) {     // k strictly ascending within panel
      const float4 av = *(const float4*)&As[kk][ty * 4];
      const float4 bv = *(const float4*)&Bs[kk][tx * 4];
      const float a4[4] = {av.x, av.y, av.z, av.w};
      const float b4[4] = {bv.x, bv.y, bv.z, bv.w};
#pragma unroll
      for (int i = 0; i < 4; ++i)
#pragma unroll
        for (int j = 0; j < 4; ++j)
          acc[i][j] = fmaf(a4[i], b4[j], acc[i][j]);
    }
    __syncthreads();

    if ((k0 + 32 == Khalf) || (k0 + 32 == K)) {   // panel fold
#pragma unroll
      for (int i = 0; i < 4; ++i)
#pragma unroll
        for (int j = 0; j < 4; ++j) {
          accC[i][j] = first ? acc[i][j] : __fadd_rn(accC[i][j], acc[i][j]);
          acc[i][j] = 0.f;
        }
      first = false;
    }
  }

  const float4 bq = *(const float4*)(bias + c0 + tx * 4);
  const float bb[4] = {bq.x, bq.y, bq.z, bq.w};
#pragma unroll
  for (int i = 0; i < 4; ++i) {
    float v[4];
#pragma unroll
    for (int j = 0; j < 4; ++j) {
      v[j] = __fadd_rn(accC[i][j], bb[j]);
      if (RELU) v[j] = fmaxf(v[j], 0.f);
    }
    float4 o; o.x = v[0]; o.y = v[1]; o.z = v[2]; o.w = v[3];
    *(float4*)(C + (size_t)(r0 + ty * 4 + i) * Nout + c0 + tx * 4) = o;
  }
}

// ---------------------------------------------------------------------------
// Row L2-normalize replicating numpy pairwise_sum bitwise (n=256) + IEEE
// sqrt/divide. One thread per row.
// ---------------------------------------------------------------------------
__global__ __launch_bounds__(256)
void l2norm_np(float* __restrict__ X)
{
  const int row = blockIdx.x * 256 + threadIdx.x;
  float* x = X + (size_t)row * ODIM;

  float S = 0.f;
#pragma unroll
  for (int h = 0; h < 2; ++h) {
    const float* a = x + h * 128;
    float r0 = __fmul_rn(a[0], a[0]);
    float r1 = __fmul_rn(a[1], a[1]);
    float r2 = __fmul_rn(a[2], a[2]);
    float r3 = __fmul_rn(a[3], a[3]);
    float r4 = __fmul_rn(a[4], a[4]);
    float r5 = __fmul_rn(a[5], a[5]);
    float r6 = __fmul_rn(a[6], a[6]);
    float r7 = __fmul_rn(a[7], a[7]);
    for (int i = 8; i < 128; i += 8) {
      r0 = __fadd_rn(r0, __fmul_rn(a[i + 0], a[i + 0]));
      r1 = __fadd_rn(r1, __fmul_rn(a[i + 1], a[i + 1]));
      r2 = __fadd_rn(r2, __fmul_rn(a[i + 2], a[i + 2]));
      r3 = __fadd_rn(r3, __fmul_rn(a[i + 3], a[i + 3]));
      r4 = __fadd_rn(r4, __fmul_rn(a[i + 4], a[i + 4]));
      r5 = __fadd_rn(r5, __fmul_rn(a[i + 5], a[i + 5]));
      r6 = __fadd_rn(r6, __fmul_rn(a[i + 6], a[i + 6]));
      r7 = __fadd_rn(r7, __fmul_rn(a[i + 7], a[i + 7]));
    }
    const float half = __fadd_rn(
        __fadd_rn(__fadd_rn(r0, r1), __fadd_rn(r2, r3)),
        __fadd_rn(__fadd_rn(r4, r5), __fadd_rn(r6, r7)));
    S = (h == 0) ? half : __fadd_rn(S, half);
  }

  const float d = fmaxf(__fsqrt_rn(S), 1e-12f);
  for (int k = 0; k < ODIM; ++k) x[k] = __fdiv_rn(x[k], d);
}

// ---------------------------------------------------------------------------
// fp32 sim = E @ E^T (K=256 <= Q: single serial-k FMA chain per element,
// bitwise-preserved) fused with exact per-row top-31.
// 64x64 tile, 256 threads, 4x4 micro-tile, BK=32.
// Top-31 per row lives in REGISTERS of the row-owner thread (tid<64):
// compare vs rv[30] is a register op; insertion is a fully-unrolled
// branchless 31-slot shift (compile-time indices only -> no scratch).
// Grid: (NROWS/64) * SPLITS.
// ---------------------------------------------------------------------------
__device__ __forceinline__ bool better(float v, int i, float v2, int i2)
{
  return (v > v2) || (v == v2 && i < i2);
}

__global__ __launch_bounds__(256)
void sim_topk(const float* __restrict__ E, float* __restrict__ lv,
              int* __restrict__ li)
{
  __shared__ float As[32][68];
  __shared__ float Bs[32][68];
  __shared__ float stile[64][65];   // (row+c)%32 scan-read banks: 2-way, free

  const int tid = threadIdx.x;
  const int tx = tid & 15, ty = tid >> 4;
  const int rb = blockIdx.x / SPLITS, sp = blockIdx.x % SPLITS;
  const int r0 = rb * 64, cbase = sp * CPS;

  // register top-31 (sorted desc by (v, -idx)); only tid<64 uses it
  float rv[TOPK];
  int   ri[TOPK];
#pragma unroll
  for (int s = 0; s < TOPK; ++s) { rv[s] = NEG_INF_F; ri[s] = IDX_MAX; }

  for (int t = 0; t < CPS / 64; ++t) {
    const int c0 = cbase + t * 64;
    float acc[4][4] = {};
#pragma unroll
    for (int k0 = 0; k0 < ODIM; k0 += 32) {
      __syncthreads();
#pragma unroll
      for (int l = 0; l < 2; ++l) {
        const int lin = l * 256 + tid;
        const int row = lin >> 3, kq = lin & 7;
        const float4 a = *(const float4*)(E + (size_t)(r0 + row) * ODIM + k0 + kq * 4);
        As[kq * 4 + 0][row] = a.x; As[kq * 4 + 1][row] = a.y;
        As[kq * 4 + 2][row] = a.z; As[kq * 4 + 3][row] = a.w;
        const float4 b = *(const float4*)(E + (size_t)(c0 + row) * ODIM + k0 + kq * 4);
        Bs[kq * 4 + 0][row] = b.x; Bs[kq * 4 + 1][row] = b.y;
        Bs[kq * 4 + 2][row] = b.z; Bs[kq * 4 + 3][row] = b.w;
      }
      __syncthreads();
#pragma unroll
      for (int kk = 0; kk < 32; ++kk) {   // serial ascending k, single chain
        const float4 av = *(const float4*)&As[kk][ty * 4];
        const float4 bv = *(const float4*)&Bs[kk][tx * 4];
        const float a4[4] = {av.x, av.y, av.z, av.w};
        const float b4[4] = {bv.x, bv.y, bv.z, bv.w};
#pragma unroll
        for (int i = 0; i < 4; ++i)
#pragma unroll
          for (int j = 0; j < 4; ++j)
            acc[i][j] = fmaf(a4[i], b4[j], acc[i][j]);
      }
    }
    __syncthreads();
#pragma unroll
    for (int i = 0; i < 4; ++i)
#pragma unroll
      for (int j = 0; j < 4; ++j)
        stile[ty * 4 + i][tx * 4 + j] = acc[i][j];
    __syncthreads();

    if (tid < 64) {                       // owner scan: row = r0 + tid
      for (int c = 0; c < 64; ++c) {
        const float v = stile[tid][c];
        const int gc = c0 + c;
        if (better(v, gc, rv[TOPK - 1], ri[TOPK - 1])) {
          // branchless unrolled sorted insert (compile-time indices)
#pragma unroll
          for (int s = TOPK - 1; s >= 1; --s) {
            const bool up = better(v, gc, rv[s - 1], ri[s - 1]);
            const bool here = better(v, gc, rv[s], ri[s]);
            const float nv = up ? rv[s - 1] : (here ? v : rv[s]);
            const int ni = up ? ri[s - 1] : (here ? gc : ri[s]);
            rv[s] = nv; ri[s] = ni;
          }
          if (better(v, gc, rv[0], ri[0])) { rv[0] = v; ri[0] = gc; }
        }
      }
    }
    // stile not overwritten until after next tile's k0-loop barriers
  }

  if (tid < 64) {
    const int row = r0 + tid;
#pragma unroll
    for (int s = 0; s < TOPK; ++s) {
      lv[(size_t)(sp * TOPK + s) * NROWS + row] = rv[s];
      li[(size_t)(sp * TOPK + s) * NROWS + row] = ri[s];
    }
  }
}

// ---------------------------------------------------------------------------
// Exact 8-way merge of sorted split lists -> final top-31 pairs per row.
// ---------------------------------------------------------------------------
__global__ __launch_bounds__(64)
void merge31(const float* __restrict__ lv, const int* __restrict__ li,
             float* __restrict__ fv, int* __restrict__ fi)
{
  const int row = blockIdx.x * 64 + threadIdx.x;
  int pos[SPLITS] = {0, 0, 0, 0, 0, 0, 0, 0};
  for (int k = 0; k < TOPK; ++k) {
    float bv = NEG_INF_F; int bi = IDX_MAX; int bs = 0;
#pragma unroll
    for (int sp = 0; sp < SPLITS; ++sp) {
      const int p = pos[sp];
      const float v = lv[(size_t)(sp * TOPK + p) * NROWS + row];
      const int ix = li[(size_t)(sp * TOPK + p) * NROWS + row];
      if (v > bv || (v == bv && ix < bi)) { bv = v; bi = ix; bs = sp; }
    }
    fv[(size_t)row * TOPK + k] = bv;
    fi[(size_t)row * TOPK + k] = bi;
    pos[bs] += 1;
  }
}

// ---------------------------------------------------------------------------
__global__ __launch_bounds__(256)
void zero_out(float4* __restrict__ out, size_t n4)
{
  size_t i = (size_t)blockIdx.x * blockDim.x + threadIdx.x;
  const size_t stride = (size_t)gridDim.x * blockDim.x;
  const float4 z = {0.f, 0.f, 0.f, 0.f};
  for (; i < n4; i += stride) out[i] = z;
}

// ---------------------------------------------------------------------------
__global__ __launch_bounds__(64)
void scatter31(const float* __restrict__ fv, const int* __restrict__ fi,
               float* __restrict__ out)
{
  const int row = blockIdx.x * 64 + threadIdx.x;
  for (int k = 0; k < TOPK; ++k) {
    const int ix = fi[(size_t)row * TOPK + k];
    const float v = fv[(size_t)row * TOPK + k];
    out[(size_t)row * NROWS + ix] = fmaxf(v, 0.f);
  }
}

// ---------------------------------------------------------------------------
extern "C" void kernel_launch(void* const* d_in, const int* in_sizes, int n_in,
                              void* d_out, int out_size, void* d_ws, size_t ws_size,
                              hipStream_t stream)
{
  const float* feat = (const float*)d_in[0];
  const float* W1 = (const float*)d_in[1];
  const float* b1 = (const float*)d_in[2];
  const float* W2 = (const float*)d_in[3];
  const float* b2 = (const float*)d_in[4];
  const float* W3 = (const float*)d_in[5];
  const float* b3 = (const float*)d_in[6];
  float* out = (float*)d_out;

  // d_out as scratch (604 MB fp32), all consumed before zero_out:
  float* X1 = (float*)d_out;                                 // 25.2 MB
  float* X2 = X1 + (size_t)NROWS * HDIM;                     // 25.2 MB
  float* lv = (float*)((char*)d_out + (size_t)128 * 1024 * 1024);  // 12.2 MB
  int* li = (int*)(lv + (size_t)SPLITS * TOPK * NROWS);      // 12.2 MB
  // d_ws (15.6 MB): E + final pairs (survive zero_out)
  float* E = (float*)d_ws;                                   // 12.6 MB
  float* fv = E + (size_t)NROWS * ODIM;                      // 1.5 MB
  int* fi = (int*)(fv + (size_t)NROWS * TOPK);               // 1.5 MB

  gemm_nt_serial<true><<<dim3(HDIM / 64, NROWS / 64), 256, 0, stream>>>(
      feat, W1, b1, X1, HDIM, FDIM);
  gemm_nt_serial<true><<<dim3(HDIM / 64, NROWS / 64), 256, 0, stream>>>(
      X1, W2, b2, X2, HDIM, HDIM);
  gemm_nt_serial<false><<<dim3(ODIM / 64, NROWS / 64), 256, 0, stream>>>(
      X2, W3, b3, E, ODIM, HDIM);
  l2norm_np<<<NROWS / 256, 256, 0, stream>>>(E);
  sim_topk<<<(NROWS / 64) * SPLITS, 256, 0, stream>>>(E, lv, li);
  merge31<<<NROWS / 64, 64, 0, stream>>>(lv, li, fv, fi);
  zero_out<<<2048, 256, 0, stream>>>((float4*)out, (size_t)NROWS * NROWS / 4);
  scatter31<<<NROWS / 64, 64, 0, stream>>>(fv, fi, out);
}

// Round 9
// 2615.239 us; speedup vs baseline: 4.5307x; 3.9060x over previous
//
#include <hip/hip_runtime.h>
#include <cstdint>
#include <cstddef>

#define NROWS 12288
#define FDIM 768
#define HDIM 512
#define ODIM 256
#define TOPK 31                // knn_k + 1

#define NEG_INF_F (-__builtin_inff())
#define IDX_MAX 0x7fffffff

__device__ __forceinline__ bool better(float v, int i, float v2, int i2)
{
  return (v > v2) || (v == v2 && i < i2);
}

// ---------------------------------------------------------------------------
// fp32 GEMM bitwise-matching OpenBLAS sgemm gemm_driver K-blocking:
// panels [K/2,K/2] for K in {512,768} (Q=384 balanced split), serial
// ascending-k FMA chain per element within panel, one fp32 add to fold.
// C = A[M][K] * B[Nout][K]^T + bias. 64x64 tile, 256 thr, 4x4 micro, BK=32.
// ---------------------------------------------------------------------------
template<bool RELU>
__global__ __launch_bounds__(256)
void gemm_nt_serial(const float* __restrict__ A, const float* __restrict__ B,
                    const float* __restrict__ bias, float* __restrict__ C,
                    int Nout, int K)
{
  __shared__ float As[32][68];
  __shared__ float Bs[32][68];
  const int tid = threadIdx.x;
  const int tx = tid & 15, ty = tid >> 4;
  const int r0 = blockIdx.y * 64, c0 = blockIdx.x * 64;
  float acc[4][4] = {};    // current panel chain
  float accC[4][4];        // folded C value (OpenBLAS C memory)
  bool first = true;
  const int Khalf = K / 2;

  for (int k0 = 0; k0 < K; k0 += 32) {
#pragma unroll
    for (int l = 0; l < 2; ++l) {
      const int lin = l * 256 + tid;
      const int row = lin >> 3, kq = lin & 7;
      const float4 a = *(const float4*)(A + (size_t)(r0 + row) * K + k0 + kq * 4);
      As[kq * 4 + 0][row] = a.x; As[kq * 4 + 1][row] = a.y;
      As[kq * 4 + 2][row] = a.z; As[kq * 4 + 3][row] = a.w;
      const float4 b = *(const float4*)(B + (size_t)(c0 + row) * K + k0 + kq * 4);
      Bs[kq * 4 + 0][row] = b.x; Bs[kq * 4 + 1][row] = b.y;
      Bs[kq * 4 + 2][row] = b.z; Bs[kq * 4 + 3][row] = b.w;
    }
    __syncthreads();
#pragma unroll
    for (int kk = 0; kk < 32; ++kk) {     // k strictly ascending within panel
      const float4 av = *(const float4*)&As[kk][ty * 4];
      const float4 bv = *(const float4*)&Bs[kk][tx * 4];
      const float a4[4] = {av.x, av.y, av.z, av.w};
      const float b4[4] = {bv.x, bv.y, bv.z, bv.w};
#pragma unroll
      for (int i = 0; i < 4; ++i)
#pragma unroll
        for (int j = 0; j < 4; ++j)
          acc[i][j] = fmaf(a4[i], b4[j], acc[i][j]);
    }
    __syncthreads();

    if ((k0 + 32 == Khalf) || (k0 + 32 == K)) {   // panel fold
#pragma unroll
      for (int i = 0; i < 4; ++i)
#pragma unroll
        for (int j = 0; j < 4; ++j) {
          accC[i][j] = first ? acc[i][j] : __fadd_rn(accC[i][j], acc[i][j]);
          acc[i][j] = 0.f;
        }
      first = false;
    }
  }

  const float4 bq = *(const float4*)(bias + c0 + tx * 4);
  const float bb[4] = {bq.x, bq.y, bq.z, bq.w};
#pragma unroll
  for (int i = 0; i < 4; ++i) {
    float v[4];
#pragma unroll
    for (int j = 0; j < 4; ++j) {
      v[j] = __fadd_rn(accC[i][j], bb[j]);
      if (RELU) v[j] = fmaxf(v[j], 0.f);
    }
    float4 o; o.x = v[0]; o.y = v[1]; o.z = v[2]; o.w = v[3];
    *(float4*)(C + (size_t)(r0 + ty * 4 + i) * Nout + c0 + tx * 4) = o;
  }
}

// ---------------------------------------------------------------------------
// Row L2-normalize replicating numpy pairwise_sum bitwise (n=256) + IEEE
// sqrt/divide. One thread per row.
// ---------------------------------------------------------------------------
__global__ __launch_bounds__(256)
void l2norm_np(float* __restrict__ X)
{
  const int row = blockIdx.x * 256 + threadIdx.x;
  float* x = X + (size_t)row * ODIM;

  float S = 0.f;
#pragma unroll
  for (int h = 0; h < 2; ++h) {
    const float* a = x + h * 128;
    float r0 = __fmul_rn(a[0], a[0]);
    float r1 = __fmul_rn(a[1], a[1]);
    float r2 = __fmul_rn(a[2], a[2]);
    float r3 = __fmul_rn(a[3], a[3]);
    float r4 = __fmul_rn(a[4], a[4]);
    float r5 = __fmul_rn(a[5], a[5]);
    float r6 = __fmul_rn(a[6], a[6]);
    float r7 = __fmul_rn(a[7], a[7]);
    for (int i = 8; i < 128; i += 8) {
      r0 = __fadd_rn(r0, __fmul_rn(a[i + 0], a[i + 0]));
      r1 = __fadd_rn(r1, __fmul_rn(a[i + 1], a[i + 1]));
      r2 = __fadd_rn(r2, __fmul_rn(a[i + 2], a[i + 2]));
      r3 = __fadd_rn(r3, __fmul_rn(a[i + 3], a[i + 3]));
      r4 = __fadd_rn(r4, __fmul_rn(a[i + 4], a[i + 4]));
      r5 = __fadd_rn(r5, __fmul_rn(a[i + 5], a[i + 5]));
      r6 = __fadd_rn(r6, __fmul_rn(a[i + 6], a[i + 6]));
      r7 = __fadd_rn(r7, __fmul_rn(a[i + 7], a[i + 7]));
    }
    const float half = __fadd_rn(
        __fadd_rn(__fadd_rn(r0, r1), __fadd_rn(r2, r3)),
        __fadd_rn(__fadd_rn(r4, r5), __fadd_rn(r6, r7)));
    S = (h == 0) ? half : __fadd_rn(S, half);
  }

  const float d = fmaxf(__fsqrt_rn(S), 1e-12f);
  for (int k = 0; k < ODIM; ++k) x[k] = __fdiv_rn(x[k], d);
}

// ---------------------------------------------------------------------------
// PURE fp32 sim GEMM: S = E @ E^T. K=256 <= Q=384 -> single serial
// ascending-k FMA chain per element (bitwise identical to previous rounds).
// 128x128 tile, 256 threads, 8x8 micro-tile, BK=32. No selection here.
// ---------------------------------------------------------------------------
__global__ __launch_bounds__(256)
void sim_gemm(const float* __restrict__ E, float* __restrict__ S)
{
  __shared__ float As[32][132];   // [k][row], pad to 132
  __shared__ float Bs[32][132];   // [k][col]
  const int tid = threadIdx.x;
  const int tx = tid & 15, ty = tid >> 4;
  const int r0 = blockIdx.y * 128, c0 = blockIdx.x * 128;
  float acc[8][8] = {};

#pragma unroll
  for (int k0 = 0; k0 < ODIM; k0 += 32) {
#pragma unroll
    for (int l = 0; l < 4; ++l) {
      const int lin = l * 256 + tid;
      const int row = lin >> 3, q = lin & 7;
      const float4 a = *(const float4*)(E + (size_t)(r0 + row) * ODIM + k0 + q * 4);
      As[q * 4 + 0][row] = a.x; As[q * 4 + 1][row] = a.y;
      As[q * 4 + 2][row] = a.z; As[q * 4 + 3][row] = a.w;
      const float4 b = *(const float4*)(E + (size_t)(c0 + row) * ODIM + k0 + q * 4);
      Bs[q * 4 + 0][row] = b.x; Bs[q * 4 + 1][row] = b.y;
      Bs[q * 4 + 2][row] = b.z; Bs[q * 4 + 3][row] = b.w;
    }
    __syncthreads();
#pragma unroll
    for (int kk = 0; kk < 32; ++kk) {   // serial ascending k, single chain
      float a8[8], b8[8];
      *(float4*)&a8[0] = *(const float4*)&As[kk][ty * 8];
      *(float4*)&a8[4] = *(const float4*)&As[kk][ty * 8 + 4];
      *(float4*)&b8[0] = *(const float4*)&Bs[kk][tx * 8];
      *(float4*)&b8[4] = *(const float4*)&Bs[kk][tx * 8 + 4];
#pragma unroll
      for (int i = 0; i < 8; ++i)
#pragma unroll
        for (int j = 0; j < 8; ++j)
          acc[i][j] = fmaf(a8[i], b8[j], acc[i][j]);
    }
    __syncthreads();
  }

#pragma unroll
  for (int i = 0; i < 8; ++i) {
    float4 o0, o1;
    o0.x = acc[i][0]; o0.y = acc[i][1]; o0.z = acc[i][2]; o0.w = acc[i][3];
    o1.x = acc[i][4]; o1.y = acc[i][5]; o1.z = acc[i][6]; o1.w = acc[i][7];
    float* dst = S + (size_t)(r0 + ty * 8 + i) * NROWS + c0 + tx * 8;
    *(float4*)dst = o0;
    *(float4*)(dst + 4) = o1;
  }
}

// ---------------------------------------------------------------------------
// Per-row exact top-31 + masked in-place rewrite. One block (256 thr) per row.
// Stage row in LDS; 31 rounds of parallel max-extraction with exact
// (value desc, index asc) order; then zero the row and scatter relu(winners).
// Thread t owns columns c = 4t + j + 1024*i  -> after a winner is cleared to
// -inf, only its owner ever reads that slot again (no extra barrier needed).
// ---------------------------------------------------------------------------
__global__ __launch_bounds__(256)
void topk_mask(float* __restrict__ S)
{
  __shared__ float vals[NROWS];          // 48 KB
  __shared__ float redv[4];
  __shared__ int   redi[4];
  __shared__ float wv[TOPK];
  __shared__ int   wi[TOPK];
  __shared__ int   bcast;

  const int tid = threadIdx.x;
  const int row = blockIdx.x;
  float* Srow = S + (size_t)row * NROWS;

#pragma unroll
  for (int i = 0; i < 12; ++i) {
    const int c = tid * 4 + i * 1024;
    *(float4*)&vals[c] = *(const float4*)(Srow + c);
  }
  __syncthreads();

  for (int k = 0; k < TOPK; ++k) {
    float bv = NEG_INF_F; int bi = IDX_MAX;
#pragma unroll
    for (int i = 0; i < 12; ++i) {
      const int c = tid * 4 + i * 1024;
      const float4 v = *(const float4*)&vals[c];
      if (better(v.x, c + 0, bv, bi)) { bv = v.x; bi = c + 0; }
      if (better(v.y, c + 1, bv, bi)) { bv = v.y; bi = c + 1; }
      if (better(v.z, c + 2, bv, bi)) { bv = v.z; bi = c + 2; }
      if (better(v.w, c + 3, bv, bi)) { bv = v.w; bi = c + 3; }
    }
#pragma unroll
    for (int o = 32; o > 0; o >>= 1) {
      const float ov = __shfl_down(bv, o);
      const int oi = __shfl_down(bi, o);
      if (better(ov, oi, bv, bi)) { bv = ov; bi = oi; }
    }
    if ((tid & 63) == 0) { redv[tid >> 6] = bv; redi[tid >> 6] = bi; }
    __syncthreads();
    if (tid == 0) {
      float fbv = redv[0]; int fbi = redi[0];
#pragma unroll
      for (int w = 1; w < 4; ++w)
        if (better(redv[w], redi[w], fbv, fbi)) { fbv = redv[w]; fbi = redi[w]; }
      wv[k] = fbv; wi[k] = fbi; bcast = fbi;
    }
    __syncthreads();
    const int widx = bcast;
    if (((widx & 1023) >> 2) == tid) vals[widx] = NEG_INF_F;  // owner clears
  }
  __syncthreads();

  const float4 z = {0.f, 0.f, 0.f, 0.f};
#pragma unroll
  for (int i = 0; i < 12; ++i) {
    const int c = tid * 4 + i * 1024;
    *(float4*)(Srow + c) = z;
  }
  __syncthreads();  // drain zero-stores before winner scatter (same addresses)
  if (tid < TOPK) Srow[wi[tid]] = fmaxf(wv[tid], 0.f);
}

// ---------------------------------------------------------------------------
extern "C" void kernel_launch(void* const* d_in, const int* in_sizes, int n_in,
                              void* d_out, int out_size, void* d_ws, size_t ws_size,
                              hipStream_t stream)
{
  const float* feat = (const float*)d_in[0];
  const float* W1 = (const float*)d_in[1];
  const float* b1 = (const float*)d_in[2];
  const float* W2 = (const float*)d_in[3];
  const float* b2 = (const float*)d_in[4];
  const float* W3 = (const float*)d_in[5];
  const float* b3 = (const float*)d_in[6];
  float* S = (float*)d_out;     // full sim matrix lives in d_out, then masked in place

  // d_ws (62.9 MB): X1, X2, E
  float* X1 = (float*)d_ws;                          // 25.2 MB
  float* X2 = X1 + (size_t)NROWS * HDIM;             // 25.2 MB
  float* E  = X2 + (size_t)NROWS * HDIM;             // 12.6 MB

  gemm_nt_serial<true><<<dim3(HDIM / 64, NROWS / 64), 256, 0, stream>>>(
      feat, W1, b1, X1, HDIM, FDIM);
  gemm_nt_serial<true><<<dim3(HDIM / 64, NROWS / 64), 256, 0, stream>>>(
      X1, W2, b2, X2, HDIM, HDIM);
  gemm_nt_serial<false><<<dim3(ODIM / 64, NROWS / 64), 256, 0, stream>>>(
      X2, W3, b3, E, ODIM, HDIM);
  l2norm_np<<<NROWS / 256, 256, 0, stream>>>(E);
  sim_gemm<<<dim3(NROWS / 128, NROWS / 128), 256, 0, stream>>>(E, S);
  topk_mask<<<NROWS, 256, 0, stream>>>(S);
}

// Round 10
// 1813.204 us; speedup vs baseline: 6.5348x; 1.4423x over previous
//
#include <hip/hip_runtime.h>
#include <cstdint>
#include <cstddef>

#define NROWS 12288
#define FDIM 768
#define HDIM 512
#define ODIM 256
#define TOPK 31                // knn_k + 1

#define NEG_INF_F (-__builtin_inff())
#define IDX_MAX 0x7fffffff

__device__ __forceinline__ bool better(float v, int i, float v2, int i2)
{
  return (v > v2) || (v == v2 && i < i2);
}

// ---------------------------------------------------------------------------
// fp32 GEMM bitwise-matching OpenBLAS sgemm gemm_driver K-blocking:
// panels [K/2,K/2] for K in {512,768} (Q=384 balanced split), serial
// ascending-k FMA chain per element within panel, one fp32 add to fold.
// C = A[M][K] * B[Nout][K]^T + bias. 64x64 tile, 256 thr, 4x4 micro, BK=32.
// ---------------------------------------------------------------------------
template<bool RELU>
__global__ __launch_bounds__(256)
void gemm_nt_serial(const float* __restrict__ A, const float* __restrict__ B,
                    const float* __restrict__ bias, float* __restrict__ C,
                    int Nout, int K)
{
  __shared__ float As[32][68];
  __shared__ float Bs[32][68];
  const int tid = threadIdx.x;
  const int tx = tid & 15, ty = tid >> 4;
  const int r0 = blockIdx.y * 64, c0 = blockIdx.x * 64;
  float acc[4][4] = {};    // current panel chain
  float accC[4][4];        // folded C value (OpenBLAS C memory)
  bool first = true;
  const int Khalf = K / 2;

  for (int k0 = 0; k0 < K; k0 += 32) {
#pragma unroll
    for (int l = 0; l < 2; ++l) {
      const int lin = l * 256 + tid;
      const int row = lin >> 3, kq = lin & 7;
      const float4 a = *(const float4*)(A + (size_t)(r0 + row) * K + k0 + kq * 4);
      As[kq * 4 + 0][row] = a.x; As[kq * 4 + 1][row] = a.y;
      As[kq * 4 + 2][row] = a.z; As[kq * 4 + 3][row] = a.w;
      const float4 b = *(const float4*)(B + (size_t)(c0 + row) * K + k0 + kq * 4);
      Bs[kq * 4 + 0][row] = b.x; Bs[kq * 4 + 1][row] = b.y;
      Bs[kq * 4 + 2][row] = b.z; Bs[kq * 4 + 3][row] = b.w;
    }
    __syncthreads();
#pragma unroll
    for (int kk = 0; kk < 32; ++kk) {     // k strictly ascending within panel
      const float4 av = *(const float4*)&As[kk][ty * 4];
      const float4 bv = *(const float4*)&Bs[kk][tx * 4];
      const float a4[4] = {av.x, av.y, av.z, av.w};
      const float b4[4] = {bv.x, bv.y, bv.z, bv.w};
#pragma unroll
      for (int i = 0; i < 4; ++i)
#pragma unroll
        for (int j = 0; j < 4; ++j)
          acc[i][j] = fmaf(a4[i], b4[j], acc[i][j]);
    }
    __syncthreads();

    if ((k0 + 32 == Khalf) || (k0 + 32 == K)) {   // panel fold
#pragma unroll
      for (int i = 0; i < 4; ++i)
#pragma unroll
        for (int j = 0; j < 4; ++j) {
          accC[i][j] = first ? acc[i][j] : __fadd_rn(accC[i][j], acc[i][j]);
          acc[i][j] = 0.f;
        }
      first = false;
    }
  }

  const float4 bq = *(const float4*)(bias + c0 + tx * 4);
  const float bb[4] = {bq.x, bq.y, bq.z, bq.w};
#pragma unroll
  for (int i = 0; i < 4; ++i) {
    float v[4];
#pragma unroll
    for (int j = 0; j < 4; ++j) {
      v[j] = __fadd_rn(accC[i][j], bb[j]);
      if (RELU) v[j] = fmaxf(v[j], 0.f);
    }
    float4 o; o.x = v[0]; o.y = v[1]; o.z = v[2]; o.w = v[3];
    *(float4*)(C + (size_t)(r0 + ty * 4 + i) * Nout + c0 + tx * 4) = o;
  }
}

// ---------------------------------------------------------------------------
// Row L2-normalize replicating numpy pairwise_sum bitwise (n=256) + IEEE
// sqrt/divide. One thread per row.
// ---------------------------------------------------------------------------
__global__ __launch_bounds__(256)
void l2norm_np(float* __restrict__ X)
{
  const int row = blockIdx.x * 256 + threadIdx.x;
  float* x = X + (size_t)row * ODIM;

  float S = 0.f;
#pragma unroll
  for (int h = 0; h < 2; ++h) {
    const float* a = x + h * 128;
    float r0 = __fmul_rn(a[0], a[0]);
    float r1 = __fmul_rn(a[1], a[1]);
    float r2 = __fmul_rn(a[2], a[2]);
    float r3 = __fmul_rn(a[3], a[3]);
    float r4 = __fmul_rn(a[4], a[4]);
    float r5 = __fmul_rn(a[5], a[5]);
    float r6 = __fmul_rn(a[6], a[6]);
    float r7 = __fmul_rn(a[7], a[7]);
    for (int i = 8; i < 128; i += 8) {
      r0 = __fadd_rn(r0, __fmul_rn(a[i + 0], a[i + 0]));
      r1 = __fadd_rn(r1, __fmul_rn(a[i + 1], a[i + 1]));
      r2 = __fadd_rn(r2, __fmul_rn(a[i + 2], a[i + 2]));
      r3 = __fadd_rn(r3, __fmul_rn(a[i + 3], a[i + 3]));
      r4 = __fadd_rn(r4, __fmul_rn(a[i + 4], a[i + 4]));
      r5 = __fadd_rn(r5, __fmul_rn(a[i + 5], a[i + 5]));
      r6 = __fadd_rn(r6, __fmul_rn(a[i + 6], a[i + 6]));
      r7 = __fadd_rn(r7, __fmul_rn(a[i + 7], a[i + 7]));
    }
    const float half = __fadd_rn(
        __fadd_rn(__fadd_rn(r0, r1), __fadd_rn(r2, r3)),
        __fadd_rn(__fadd_rn(r4, r5), __fadd_rn(r6, r7)));
    S = (h == 0) ? half : __fadd_rn(S, half);
  }

  const float d = fmaxf(__fsqrt_rn(S), 1e-12f);
  for (int k = 0; k < ODIM; ++k) x[k] = __fdiv_rn(x[k], d);
}

// ---------------------------------------------------------------------------
// PURE fp32 sim GEMM: S = E @ E^T. K=256 <= Q=384 -> single serial
// ascending-k FMA chain per element (bitwise identical to previous rounds).
// 128x128 tile, 256 threads, 8x8 micro-tile, BK=32. No selection here.
// ---------------------------------------------------------------------------
__global__ __launch_bounds__(256)
void sim_gemm(const float* __restrict__ E, float* __restrict__ S)
{
  __shared__ float As[32][132];   // [k][row], pad to 132
  __shared__ float Bs[32][132];   // [k][col]
  const int tid = threadIdx.x;
  const int tx = tid & 15, ty = tid >> 4;
  const int r0 = blockIdx.y * 128, c0 = blockIdx.x * 128;
  float acc[8][8] = {};

#pragma unroll
  for (int k0 = 0; k0 < ODIM; k0 += 32) {
#pragma unroll
    for (int l = 0; l < 4; ++l) {
      const int lin = l * 256 + tid;
      const int row = lin >> 3, q = lin & 7;
      const float4 a = *(const float4*)(E + (size_t)(r0 + row) * ODIM + k0 + q * 4);
      As[q * 4 + 0][row] = a.x; As[q * 4 + 1][row] = a.y;
      As[q * 4 + 2][row] = a.z; As[q * 4 + 3][row] = a.w;
      const float4 b = *(const float4*)(E + (size_t)(c0 + row) * ODIM + k0 + q * 4);
      Bs[q * 4 + 0][row] = b.x; Bs[q * 4 + 1][row] = b.y;
      Bs[q * 4 + 2][row] = b.z; Bs[q * 4 + 3][row] = b.w;
    }
    __syncthreads();
#pragma unroll
    for (int kk = 0; kk < 32; ++kk) {   // serial ascending k, single chain
      float a8[8], b8[8];
      *(float4*)&a8[0] = *(const float4*)&As[kk][ty * 8];
      *(float4*)&a8[4] = *(const float4*)&As[kk][ty * 8 + 4];
      *(float4*)&b8[0] = *(const float4*)&Bs[kk][tx * 8];
      *(float4*)&b8[4] = *(const float4*)&Bs[kk][tx * 8 + 4];
#pragma unroll
      for (int i = 0; i < 8; ++i)
#pragma unroll
        for (int j = 0; j < 8; ++j)
          acc[i][j] = fmaf(a8[i], b8[j], acc[i][j]);
    }
    __syncthreads();
  }

#pragma unroll
  for (int i = 0; i < 8; ++i) {
    float4 o0, o1;
    o0.x = acc[i][0]; o0.y = acc[i][1]; o0.z = acc[i][2]; o0.w = acc[i][3];
    o1.x = acc[i][4]; o1.y = acc[i][5]; o1.z = acc[i][6]; o1.w = acc[i][7];
    float* dst = S + (size_t)(r0 + ty * 8 + i) * NROWS + c0 + tx * 8;
    *(float4*)dst = o0;
    *(float4*)(dst + 4) = o1;
  }
}

// ---------------------------------------------------------------------------
// Per-row exact top-31 + masked in-place rewrite. One block (256 thr) per row.
// Row lives in REGISTERS (12 float4/thread). Each thread caches its local
// top-2 (v0,i0,v1,i1). Winner of each round == unique owner's v0 (strict
// total order), so per round only that owner updates: promote v1, set the
// 48-bit dead mask, and lazily rebuild from registers if its cache is empty.
// No per-round rescans, no LDS value array.
// Thread t owns columns c = 4t + j + 1024*i (i<12, j<4).
// ---------------------------------------------------------------------------
__device__ __forceinline__ void ins2(float val, int idx,
                                     float& v0, int& i0, float& v1, int& i1)
{
  const bool b0 = better(val, idx, v0, i0);
  const bool b1 = better(val, idx, v1, i1);
  const float nv1 = b0 ? v0 : (b1 ? val : v1);
  const int   ni1 = b0 ? i0 : (b1 ? idx : i1);
  v0 = b0 ? val : v0; i0 = b0 ? idx : i0;
  v1 = nv1; i1 = ni1;
}

__device__ __forceinline__ void rebuild2(const float4 (&v)[12], uint64_t dead,
                                         int tid, float& v0, int& i0,
                                         float& v1, int& i1)
{
  v0 = NEG_INF_F; i0 = IDX_MAX; v1 = NEG_INF_F; i1 = IDX_MAX;
#pragma unroll
  for (int i = 0; i < 12; ++i) {
    const int cbase = tid * 4 + i * 1024;
    float e;
    e = ((dead >> (i * 4 + 0)) & 1ull) ? NEG_INF_F : v[i].x;
    ins2(e, cbase + 0, v0, i0, v1, i1);
    e = ((dead >> (i * 4 + 1)) & 1ull) ? NEG_INF_F : v[i].y;
    ins2(e, cbase + 1, v0, i0, v1, i1);
    e = ((dead >> (i * 4 + 2)) & 1ull) ? NEG_INF_F : v[i].z;
    ins2(e, cbase + 2, v0, i0, v1, i1);
    e = ((dead >> (i * 4 + 3)) & 1ull) ? NEG_INF_F : v[i].w;
    ins2(e, cbase + 3, v0, i0, v1, i1);
  }
}

__global__ __launch_bounds__(256)
void topk_mask(float* __restrict__ S)
{
  __shared__ float redv[4];
  __shared__ int   redi[4];
  __shared__ float wv[TOPK];
  __shared__ int   wi[TOPK];
  __shared__ int   bcast;

  const int tid = threadIdx.x;
  const int row = blockIdx.x;
  float* Srow = S + (size_t)row * NROWS;

  float4 v[12];
#pragma unroll
  for (int i = 0; i < 12; ++i)
    v[i] = *(const float4*)(Srow + tid * 4 + i * 1024);

  uint64_t dead = 0;
  float v0, v1; int i0, i1;
  rebuild2(v, dead, tid, v0, i0, v1, i1);

  for (int k = 0; k < TOPK; ++k) {
    // block-wide argmax of cached tops
    float bv = v0; int bi = i0;
#pragma unroll
    for (int o = 32; o > 0; o >>= 1) {
      const float ov = __shfl_down(bv, o);
      const int oi = __shfl_down(bi, o);
      if (better(ov, oi, bv, bi)) { bv = ov; bi = oi; }
    }
    if ((tid & 63) == 0) { redv[tid >> 6] = bv; redi[tid >> 6] = bi; }
    __syncthreads();
    if (tid == 0) {
      float fbv = redv[0]; int fbi = redi[0];
#pragma unroll
      for (int w = 1; w < 4; ++w)
        if (better(redv[w], redi[w], fbv, fbi)) { fbv = redv[w]; fbi = redi[w]; }
      wv[k] = fbv; wi[k] = fbi; bcast = fbi;
    }
    __syncthreads();
    const int widx = bcast;
    if (i0 == widx) {                    // unique owner: update cache
      const int slot = ((widx >> 10) << 2) | (widx & 3);
      dead |= (1ull << slot);
      v0 = v1; i0 = i1;
      v1 = NEG_INF_F; i1 = IDX_MAX;
      if (i0 == IDX_MAX) rebuild2(v, dead, tid, v0, i0, v1, i1);
    }
  }
  // last round ended with __syncthreads(); wv/wi complete

  const float4 z = {0.f, 0.f, 0.f, 0.f};
#pragma unroll
  for (int i = 0; i < 12; ++i)
    *(float4*)(Srow + tid * 4 + i * 1024) = z;
  __syncthreads();  // order zero-stores before winner scatter
  if (tid < TOPK) Srow[wi[tid]] = fmaxf(wv[tid], 0.f);
}

// ---------------------------------------------------------------------------
extern "C" void kernel_launch(void* const* d_in, const int* in_sizes, int n_in,
                              void* d_out, int out_size, void* d_ws, size_t ws_size,
                              hipStream_t stream)
{
  const float* feat = (const float*)d_in[0];
  const float* W1 = (const float*)d_in[1];
  const float* b1 = (const float*)d_in[2];
  const float* W2 = (const float*)d_in[3];
  const float* b2 = (const float*)d_in[4];
  const float* W3 = (const float*)d_in[5];
  const float* b3 = (const float*)d_in[6];
  float* S = (float*)d_out;   // full sim matrix in d_out, masked in place

  // d_ws (62.9 MB): X1, X2, E
  float* X1 = (float*)d_ws;                          // 25.2 MB
  float* X2 = X1 + (size_t)NROWS * HDIM;             // 25.2 MB
  float* E  = X2 + (size_t)NROWS * HDIM;             // 12.6 MB

  gemm_nt_serial<true><<<dim3(HDIM / 64, NROWS / 64), 256, 0, stream>>>(
      feat, W1, b1, X1, HDIM, FDIM);
  gemm_nt_serial<true><<<dim3(HDIM / 64, NROWS / 64), 256, 0, stream>>>(
      X1, W2, b2, X2, HDIM, HDIM);
  gemm_nt_serial<false><<<dim3(ODIM / 64, NROWS / 64), 256, 0, stream>>>(
      X2, W3, b3, E, ODIM, HDIM);
  l2norm_np<<<NROWS / 256, 256, 0, stream>>>(E);
  sim_gemm<<<dim3(NROWS / 128, NROWS / 128), 256, 0, stream>>>(E, S);
  topk_mask<<<NROWS, 256, 0, stream>>>(S);
}

// Round 11
// 1806.584 us; speedup vs baseline: 6.5587x; 1.0037x over previous
//
#include <hip/hip_runtime.h>
#include <cstdint>
#include <cstddef>

#define NROWS 12288
#define FDIM 768
#define HDIM 512
#define ODIM 256
#define TOPK 31                // knn_k + 1

#define NEG_INF_F (-__builtin_inff())
#define IDX_MAX 0x7fffffff

__device__ __forceinline__ bool better(float v, int i, float v2, int i2)
{
  return (v > v2) || (v == v2 && i < i2);
}

// ---------------------------------------------------------------------------
// fp32 GEMM bitwise-matching OpenBLAS sgemm gemm_driver K-blocking:
// panels [K/2,K/2] for K in {512,768} (Q=384 balanced split), serial
// ascending-k FMA chain per element within panel, one fp32 add to fold.
// C = A[M][K] * B[Nout][K]^T + bias. 64x64 tile, 256 thr, 4x4 micro, BK=32.
// ---------------------------------------------------------------------------
template<bool RELU>
__global__ __launch_bounds__(256)
void gemm_nt_serial(const float* __restrict__ A, const float* __restrict__ B,
                    const float* __restrict__ bias, float* __restrict__ C,
                    int Nout, int K)
{
  __shared__ float As[32][68];
  __shared__ float Bs[32][68];
  const int tid = threadIdx.x;
  const int tx = tid & 15, ty = tid >> 4;
  const int r0 = blockIdx.y * 64, c0 = blockIdx.x * 64;
  float acc[4][4] = {};    // current panel chain
  float accC[4][4];        // folded C value (OpenBLAS C memory)
  bool first = true;
  const int Khalf = K / 2;

  for (int k0 = 0; k0 < K; k0 += 32) {
#pragma unroll
    for (int l = 0; l < 2; ++l) {
      const int lin = l * 256 + tid;
      const int row = lin >> 3, kq = lin & 7;
      const float4 a = *(const float4*)(A + (size_t)(r0 + row) * K + k0 + kq * 4);
      As[kq * 4 + 0][row] = a.x; As[kq * 4 + 1][row] = a.y;
      As[kq * 4 + 2][row] = a.z; As[kq * 4 + 3][row] = a.w;
      const float4 b = *(const float4*)(B + (size_t)(c0 + row) * K + k0 + kq * 4);
      Bs[kq * 4 + 0][row] = b.x; Bs[kq * 4 + 1][row] = b.y;
      Bs[kq * 4 + 2][row] = b.z; Bs[kq * 4 + 3][row] = b.w;
    }
    __syncthreads();
#pragma unroll
    for (int kk = 0; kk < 32; ++kk) {     // k strictly ascending within panel
      const float4 av = *(const float4*)&As[kk][ty * 4];
      const float4 bv = *(const float4*)&Bs[kk][tx * 4];
      const float a4[4] = {av.x, av.y, av.z, av.w};
      const float b4[4] = {bv.x, bv.y, bv.z, bv.w};
#pragma unroll
      for (int i = 0; i < 4; ++i)
#pragma unroll
        for (int j = 0; j < 4; ++j)
          acc[i][j] = fmaf(a4[i], b4[j], acc[i][j]);
    }
    __syncthreads();

    if ((k0 + 32 == Khalf) || (k0 + 32 == K)) {   // panel fold
#pragma unroll
      for (int i = 0; i < 4; ++i)
#pragma unroll
        for (int j = 0; j < 4; ++j) {
          accC[i][j] = first ? acc[i][j] : __fadd_rn(accC[i][j], acc[i][j]);
          acc[i][j] = 0.f;
        }
      first = false;
    }
  }

  const float4 bq = *(const float4*)(bias + c0 + tx * 4);
  const float bb[4] = {bq.x, bq.y, bq.z, bq.w};
#pragma unroll
  for (int i = 0; i < 4; ++i) {
    float v[4];
#pragma unroll
    for (int j = 0; j < 4; ++j) {
      v[j] = __fadd_rn(accC[i][j], bb[j]);
      if (RELU) v[j] = fmaxf(v[j], 0.f);
    }
    float4 o; o.x = v[0]; o.y = v[1]; o.z = v[2]; o.w = v[3];
    *(float4*)(C + (size_t)(r0 + ty * 4 + i) * Nout + c0 + tx * 4) = o;
  }
}

// ---------------------------------------------------------------------------
// Row L2-normalize replicating numpy pairwise_sum bitwise (n=256) + IEEE
// sqrt/divide. One thread per row.
// ---------------------------------------------------------------------------
__global__ __launch_bounds__(256)
void l2norm_np(float* __restrict__ X)
{
  const int row = blockIdx.x * 256 + threadIdx.x;
  float* x = X + (size_t)row * ODIM;

  float S = 0.f;
#pragma unroll
  for (int h = 0; h < 2; ++h) {
    const float* a = x + h * 128;
    float r0 = __fmul_rn(a[0], a[0]);
    float r1 = __fmul_rn(a[1], a[1]);
    float r2 = __fmul_rn(a[2], a[2]);
    float r3 = __fmul_rn(a[3], a[3]);
    float r4 = __fmul_rn(a[4], a[4]);
    float r5 = __fmul_rn(a[5], a[5]);
    float r6 = __fmul_rn(a[6], a[6]);
    float r7 = __fmul_rn(a[7], a[7]);
    for (int i = 8; i < 128; i += 8) {
      r0 = __fadd_rn(r0, __fmul_rn(a[i + 0], a[i + 0]));
      r1 = __fadd_rn(r1, __fmul_rn(a[i + 1], a[i + 1]));
      r2 = __fadd_rn(r2, __fmul_rn(a[i + 2], a[i + 2]));
      r3 = __fadd_rn(r3, __fmul_rn(a[i + 3], a[i + 3]));
      r4 = __fadd_rn(r4, __fmul_rn(a[i + 4], a[i + 4]));
      r5 = __fadd_rn(r5, __fmul_rn(a[i + 5], a[i + 5]));
      r6 = __fadd_rn(r6, __fmul_rn(a[i + 6], a[i + 6]));
      r7 = __fadd_rn(r7, __fmul_rn(a[i + 7], a[i + 7]));
    }
    const float half = __fadd_rn(
        __fadd_rn(__fadd_rn(r0, r1), __fadd_rn(r2, r3)),
        __fadd_rn(__fadd_rn(r4, r5), __fadd_rn(r6, r7)));
    S = (h == 0) ? half : __fadd_rn(S, half);
  }

  const float d = fmaxf(__fsqrt_rn(S), 1e-12f);
  for (int k = 0; k < ODIM; ++k) x[k] = __fdiv_rn(x[k], d);
}

// ---------------------------------------------------------------------------
// PURE fp32 sim GEMM: S = E @ E^T. K=256 <= Q=384 -> single serial
// ascending-k FMA chain per element (bitwise identical).
// 128x128 tile, 256 threads, 8x8 micro-tile, BK=32.
// Thread column ownership is SPLIT: cols {tx*4..+3} and {64+tx*4..+3} so the
// two Bs micro-reads hit banks (tx*4)%32 -> 2-way aliasing only (free),
// instead of the 4-way conflict of contiguous tx*8 ownership.
// ---------------------------------------------------------------------------
__global__ __launch_bounds__(256)
void sim_gemm(const float* __restrict__ E, float* __restrict__ S)
{
  __shared__ float As[32][132];   // [k][row], pad to 132
  __shared__ float Bs[32][132];   // [k][col]
  const int tid = threadIdx.x;
  const int tx = tid & 15, ty = tid >> 4;
  const int r0 = blockIdx.y * 128, c0 = blockIdx.x * 128;
  float acc[8][8] = {};

#pragma unroll
  for (int k0 = 0; k0 < ODIM; k0 += 32) {
#pragma unroll
    for (int l = 0; l < 4; ++l) {
      const int lin = l * 256 + tid;
      const int row = lin >> 3, q = lin & 7;
      const float4 a = *(const float4*)(E + (size_t)(r0 + row) * ODIM + k0 + q * 4);
      As[q * 4 + 0][row] = a.x; As[q * 4 + 1][row] = a.y;
      As[q * 4 + 2][row] = a.z; As[q * 4 + 3][row] = a.w;
      const float4 b = *(const float4*)(E + (size_t)(c0 + row) * ODIM + k0 + q * 4);
      Bs[q * 4 + 0][row] = b.x; Bs[q * 4 + 1][row] = b.y;
      Bs[q * 4 + 2][row] = b.z; Bs[q * 4 + 3][row] = b.w;
    }
    __syncthreads();
#pragma unroll
    for (int kk = 0; kk < 32; ++kk) {   // serial ascending k, single chain
      float a8[8], b8[8];
      *(float4*)&a8[0] = *(const float4*)&As[kk][ty * 8];
      *(float4*)&a8[4] = *(const float4*)&As[kk][ty * 8 + 4];
      *(float4*)&b8[0] = *(const float4*)&Bs[kk][tx * 4];        // 2-way banks
      *(float4*)&b8[4] = *(const float4*)&Bs[kk][64 + tx * 4];   // 2-way banks
#pragma unroll
      for (int i = 0; i < 8; ++i)
#pragma unroll
        for (int j = 0; j < 8; ++j)
          acc[i][j] = fmaf(a8[i], b8[j], acc[i][j]);
    }
    __syncthreads();
  }

#pragma unroll
  for (int i = 0; i < 8; ++i) {
    float4 o0, o1;
    o0.x = acc[i][0]; o0.y = acc[i][1]; o0.z = acc[i][2]; o0.w = acc[i][3];
    o1.x = acc[i][4]; o1.y = acc[i][5]; o1.z = acc[i][6]; o1.w = acc[i][7];
    float* dst = S + (size_t)(r0 + ty * 8 + i) * NROWS + c0;
    *(float4*)(dst + tx * 4) = o0;
    *(float4*)(dst + 64 + tx * 4) = o1;
  }
}

// ---------------------------------------------------------------------------
// Per-row exact top-31 + masked in-place rewrite. One block (256 thr) per row.
// Row lives in REGISTERS (12 float4/thread); per-thread top-2 cache; one
// unique owner updates per round (strict total order); lazy rebuild with a
// 48-bit dead mask. No per-round rescans, no LDS value array.
// Thread t owns columns c = 4t + j + 1024*i (i<12, j<4).
// ---------------------------------------------------------------------------
__device__ __forceinline__ void ins2(float val, int idx,
                                     float& v0, int& i0, float& v1, int& i1)
{
  const bool b0 = better(val, idx, v0, i0);
  const bool b1 = better(val, idx, v1, i1);
  const float nv1 = b0 ? v0 : (b1 ? val : v1);
  const int   ni1 = b0 ? i0 : (b1 ? idx : i1);
  v0 = b0 ? val : v0; i0 = b0 ? idx : i0;
  v1 = nv1; i1 = ni1;
}

__device__ __forceinline__ void rebuild2(const float4 (&v)[12], uint64_t dead,
                                         int tid, float& v0, int& i0,
                                         float& v1, int& i1)
{
  v0 = NEG_INF_F; i0 = IDX_MAX; v1 = NEG_INF_F; i1 = IDX_MAX;
#pragma unroll
  for (int i = 0; i < 12; ++i) {
    const int cbase = tid * 4 + i * 1024;
    float e;
    e = ((dead >> (i * 4 + 0)) & 1ull) ? NEG_INF_F : v[i].x;
    ins2(e, cbase + 0, v0, i0, v1, i1);
    e = ((dead >> (i * 4 + 1)) & 1ull) ? NEG_INF_F : v[i].y;
    ins2(e, cbase + 1, v0, i0, v1, i1);
    e = ((dead >> (i * 4 + 2)) & 1ull) ? NEG_INF_F : v[i].z;
    ins2(e, cbase + 2, v0, i0, v1, i1);
    e = ((dead >> (i * 4 + 3)) & 1ull) ? NEG_INF_F : v[i].w;
    ins2(e, cbase + 3, v0, i0, v1, i1);
  }
}

__global__ __launch_bounds__(256)
void topk_mask(float* __restrict__ S)
{
  __shared__ float redv[4];
  __shared__ int   redi[4];
  __shared__ float wv[TOPK];
  __shared__ int   wi[TOPK];
  __shared__ int   bcast;

  const int tid = threadIdx.x;
  const int row = blockIdx.x;
  float* Srow = S + (size_t)row * NROWS;

  float4 v[12];
#pragma unroll
  for (int i = 0; i < 12; ++i)
    v[i] = *(const float4*)(Srow + tid * 4 + i * 1024);

  uint64_t dead = 0;
  float v0, v1; int i0, i1;
  rebuild2(v, dead, tid, v0, i0, v1, i1);

  for (int k = 0; k < TOPK; ++k) {
    float bv = v0; int bi = i0;
#pragma unroll
    for (int o = 32; o > 0; o >>= 1) {
      const float ov = __shfl_down(bv, o);
      const int oi = __shfl_down(bi, o);
      if (better(ov, oi, bv, bi)) { bv = ov; bi = oi; }
    }
    if ((tid & 63) == 0) { redv[tid >> 6] = bv; redi[tid >> 6] = bi; }
    __syncthreads();
    if (tid == 0) {
      float fbv = redv[0]; int fbi = redi[0];
#pragma unroll
      for (int w = 1; w < 4; ++w)
        if (better(redv[w], redi[w], fbv, fbi)) { fbv = redv[w]; fbi = redi[w]; }
      wv[k] = fbv; wi[k] = fbi; bcast = fbi;
    }
    __syncthreads();
    const int widx = bcast;
    if (i0 == widx) {                    // unique owner: update cache
      const int slot = ((widx >> 10) << 2) | (widx & 3);
      dead |= (1ull << slot);
      v0 = v1; i0 = i1;
      v1 = NEG_INF_F; i1 = IDX_MAX;
      if (i0 == IDX_MAX) rebuild2(v, dead, tid, v0, i0, v1, i1);
    }
  }

  const float4 z = {0.f, 0.f, 0.f, 0.f};
#pragma unroll
  for (int i = 0; i < 12; ++i)
    *(float4*)(Srow + tid * 4 + i * 1024) = z;
  __syncthreads();  // order zero-stores before winner scatter
  if (tid < TOPK) Srow[wi[tid]] = fmaxf(wv[tid], 0.f);
}

// ---------------------------------------------------------------------------
extern "C" void kernel_launch(void* const* d_in, const int* in_sizes, int n_in,
                              void* d_out, int out_size, void* d_ws, size_t ws_size,
                              hipStream_t stream)
{
  const float* feat = (const float*)d_in[0];
  const float* W1 = (const float*)d_in[1];
  const float* b1 = (const float*)d_in[2];
  const float* W2 = (const float*)d_in[3];
  const float* b2 = (const float*)d_in[4];
  const float* W3 = (const float*)d_in[5];
  const float* b3 = (const float*)d_in[6];
  float* S = (float*)d_out;   // full sim matrix in d_out, masked in place

  // d_ws (62.9 MB): X1, X2, E
  float* X1 = (float*)d_ws;                          // 25.2 MB
  float* X2 = X1 + (size_t)NROWS * HDIM;             // 25.2 MB
  float* E  = X2 + (size_t)NROWS * HDIM;             // 12.6 MB

  gemm_nt_serial<true><<<dim3(HDIM / 64, NROWS / 64), 256, 0, stream>>>(
      feat, W1, b1, X1, HDIM, FDIM);
  gemm_nt_serial<true><<<dim3(HDIM / 64, NROWS / 64), 256, 0, stream>>>(
      X1, W2, b2, X2, HDIM, HDIM);
  gemm_nt_serial<false><<<dim3(ODIM / 64, NROWS / 64), 256, 0, stream>>>(
      X2, W3, b3, E, ODIM, HDIM);
  l2norm_np<<<NROWS / 256, 256, 0, stream>>>(E);
  sim_gemm<<<dim3(NROWS / 128, NROWS / 128), 256, 0, stream>>>(E, S);
  topk_mask<<<NROWS, 256, 0, stream>>>(S);
}

// Round 12
// 1752.336 us; speedup vs baseline: 6.7618x; 1.0310x over previous
//
#include <hip/hip_runtime.h>
#include <cstdint>
#include <cstddef>

#define NROWS 12288
#define FDIM 768
#define HDIM 512
#define ODIM 256
#define TOPK 31                // knn_k + 1

#define NEG_INF_F (-__builtin_inff())
#define IDX_MAX 0x7fffffff

__device__ __forceinline__ bool better(float v, int i, float v2, int i2)
{
  return (v > v2) || (v == v2 && i < i2);
}

// ---------------------------------------------------------------------------
// fp32 GEMM bitwise-matching OpenBLAS sgemm gemm_driver K-blocking:
// panels [K/2,K/2] for K in {512,768} (Q=384 balanced split), serial
// ascending-k FMA chain per element within panel, one fp32 add to fold.
// LDS k-rows are BIT-TRANSPOSE swizzled (logical kk -> physical
// ((kk&3)<<3)|(kk>>2)) so staging writes land in banks 4q+g (2-way, free)
// instead of 16q-parity 4-way conflicts. Reads use the same compile-time
// permutation; per-element FMA order is untouched (bitwise identical).
// C = A[M][K] * B[Nout][K]^T + bias. 64x64 tile, 256 thr, 4x4 micro, BK=32.
// ---------------------------------------------------------------------------
template<bool RELU>
__global__ __launch_bounds__(256)
void gemm_nt_serial(const float* __restrict__ A, const float* __restrict__ B,
                    const float* __restrict__ bias, float* __restrict__ C,
                    int Nout, int K)
{
  __shared__ float As[32][68];
  __shared__ float Bs[32][68];
  const int tid = threadIdx.x;
  const int tx = tid & 15, ty = tid >> 4;
  const int r0 = blockIdx.y * 64, c0 = blockIdx.x * 64;
  float acc[4][4] = {};    // current panel chain
  float accC[4][4];        // folded C value (OpenBLAS C memory)
  bool first = true;
  const int Khalf = K / 2;

  for (int k0 = 0; k0 < K; k0 += 32) {
#pragma unroll
    for (int l = 0; l < 2; ++l) {
      const int lin = l * 256 + tid;
      const int row = lin >> 3, kq = lin & 7;
      const float4 a = *(const float4*)(A + (size_t)(r0 + row) * K + k0 + kq * 4);
      As[kq + 0][row] = a.x; As[kq + 8][row] = a.y;       // phys row 8j+q
      As[kq + 16][row] = a.z; As[kq + 24][row] = a.w;
      const float4 b = *(const float4*)(B + (size_t)(c0 + row) * K + k0 + kq * 4);
      Bs[kq + 0][row] = b.x; Bs[kq + 8][row] = b.y;
      Bs[kq + 16][row] = b.z; Bs[kq + 24][row] = b.w;
    }
    __syncthreads();
#pragma unroll
    for (int kk = 0; kk < 32; ++kk) {     // k strictly ascending within panel
      const int kp = ((kk & 3) << 3) | (kk >> 2);         // physical row
      const float4 av = *(const float4*)&As[kp][ty * 4];
      const float4 bv = *(const float4*)&Bs[kp][tx * 4];
      const float a4[4] = {av.x, av.y, av.z, av.w};
      const float b4[4] = {bv.x, bv.y, bv.z, bv.w};
#pragma unroll
      for (int i = 0; i < 4; ++i)
#pragma unroll
        for (int j = 0; j < 4; ++j)
          acc[i][j] = fmaf(a4[i], b4[j], acc[i][j]);
    }
    __syncthreads();

    if ((k0 + 32 == Khalf) || (k0 + 32 == K)) {   // panel fold
#pragma unroll
      for (int i = 0; i < 4; ++i)
#pragma unroll
        for (int j = 0; j < 4; ++j) {
          accC[i][j] = first ? acc[i][j] : __fadd_rn(accC[i][j], acc[i][j]);
          acc[i][j] = 0.f;
        }
      first = false;
    }
  }

  const float4 bq = *(const float4*)(bias + c0 + tx * 4);
  const float bb[4] = {bq.x, bq.y, bq.z, bq.w};
#pragma unroll
  for (int i = 0; i < 4; ++i) {
    float v[4];
#pragma unroll
    for (int j = 0; j < 4; ++j) {
      v[j] = __fadd_rn(accC[i][j], bb[j]);
      if (RELU) v[j] = fmaxf(v[j], 0.f);
    }
    float4 o; o.x = v[0]; o.y = v[1]; o.z = v[2]; o.w = v[3];
    *(float4*)(C + (size_t)(r0 + ty * 4 + i) * Nout + c0 + tx * 4) = o;
  }
}

// ---------------------------------------------------------------------------
// Row L2-normalize replicating numpy pairwise_sum bitwise (n=256) + IEEE
// sqrt/divide. One thread per row.
// ---------------------------------------------------------------------------
__global__ __launch_bounds__(256)
void l2norm_np(float* __restrict__ X)
{
  const int row = blockIdx.x * 256 + threadIdx.x;
  float* x = X + (size_t)row * ODIM;

  float S = 0.f;
#pragma unroll
  for (int h = 0; h < 2; ++h) {
    const float* a = x + h * 128;
    float r0 = __fmul_rn(a[0], a[0]);
    float r1 = __fmul_rn(a[1], a[1]);
    float r2 = __fmul_rn(a[2], a[2]);
    float r3 = __fmul_rn(a[3], a[3]);
    float r4 = __fmul_rn(a[4], a[4]);
    float r5 = __fmul_rn(a[5], a[5]);
    float r6 = __fmul_rn(a[6], a[6]);
    float r7 = __fmul_rn(a[7], a[7]);
    for (int i = 8; i < 128; i += 8) {
      r0 = __fadd_rn(r0, __fmul_rn(a[i + 0], a[i + 0]));
      r1 = __fadd_rn(r1, __fmul_rn(a[i + 1], a[i + 1]));
      r2 = __fadd_rn(r2, __fmul_rn(a[i + 2], a[i + 2]));
      r3 = __fadd_rn(r3, __fmul_rn(a[i + 3], a[i + 3]));
      r4 = __fadd_rn(r4, __fmul_rn(a[i + 4], a[i + 4]));
      r5 = __fadd_rn(r5, __fmul_rn(a[i + 5], a[i + 5]));
      r6 = __fadd_rn(r6, __fmul_rn(a[i + 6], a[i + 6]));
      r7 = __fadd_rn(r7, __fmul_rn(a[i + 7], a[i + 7]));
    }
    const float half = __fadd_rn(
        __fadd_rn(__fadd_rn(r0, r1), __fadd_rn(r2, r3)),
        __fadd_rn(__fadd_rn(r4, r5), __fadd_rn(r6, r7)));
    S = (h == 0) ? half : __fadd_rn(S, half);
  }

  const float d = fmaxf(__fsqrt_rn(S), 1e-12f);
  for (int k = 0; k < ODIM; ++k) x[k] = __fdiv_rn(x[k], d);
}

// ---------------------------------------------------------------------------
// PURE fp32 sim GEMM: S = E @ E^T. K=256 <= Q=384 -> single serial
// ascending-k FMA chain per element (bitwise identical).
// 128x128 tile, 256 threads, 8x8 micro-tile (split columns: tx*4 and
// 64+tx*4, 2-way banks), BK=32, bit-transpose-swizzled LDS k-rows so
// staging writes are 2-way (free) instead of 4-way.
// ---------------------------------------------------------------------------
__global__ __launch_bounds__(256)
void sim_gemm(const float* __restrict__ E, float* __restrict__ S)
{
  __shared__ float As[32][132];   // [k_phys][row], pad 132
  __shared__ float Bs[32][132];   // [k_phys][col]
  const int tid = threadIdx.x;
  const int tx = tid & 15, ty = tid >> 4;
  const int r0 = blockIdx.y * 128, c0 = blockIdx.x * 128;
  float acc[8][8] = {};

#pragma unroll
  for (int k0 = 0; k0 < ODIM; k0 += 32) {
#pragma unroll
    for (int l = 0; l < 4; ++l) {
      const int lin = l * 256 + tid;
      const int row = lin >> 3, q = lin & 7;
      const float4 a = *(const float4*)(E + (size_t)(r0 + row) * ODIM + k0 + q * 4);
      As[q + 0][row] = a.x; As[q + 8][row] = a.y;        // phys row 8j+q
      As[q + 16][row] = a.z; As[q + 24][row] = a.w;
      const float4 b = *(const float4*)(E + (size_t)(c0 + row) * ODIM + k0 + q * 4);
      Bs[q + 0][row] = b.x; Bs[q + 8][row] = b.y;
      Bs[q + 16][row] = b.z; Bs[q + 24][row] = b.w;
    }
    __syncthreads();
#pragma unroll
    for (int kk = 0; kk < 32; ++kk) {   // serial ascending logical k
      const int kp = ((kk & 3) << 3) | (kk >> 2);        // physical row
      float a8[8], b8[8];
      *(float4*)&a8[0] = *(const float4*)&As[kp][ty * 8];
      *(float4*)&a8[4] = *(const float4*)&As[kp][ty * 8 + 4];
      *(float4*)&b8[0] = *(const float4*)&Bs[kp][tx * 4];
      *(float4*)&b8[4] = *(const float4*)&Bs[kp][64 + tx * 4];
#pragma unroll
      for (int i = 0; i < 8; ++i)
#pragma unroll
        for (int j = 0; j < 8; ++j)
          acc[i][j] = fmaf(a8[i], b8[j], acc[i][j]);
    }
    __syncthreads();
  }

#pragma unroll
  for (int i = 0; i < 8; ++i) {
    float4 o0, o1;
    o0.x = acc[i][0]; o0.y = acc[i][1]; o0.z = acc[i][2]; o0.w = acc[i][3];
    o1.x = acc[i][4]; o1.y = acc[i][5]; o1.z = acc[i][6]; o1.w = acc[i][7];
    float* dst = S + (size_t)(r0 + ty * 8 + i) * NROWS + c0;
    *(float4*)(dst + tx * 4) = o0;
    *(float4*)(dst + 64 + tx * 4) = o1;
  }
}

// ---------------------------------------------------------------------------
// Per-row exact top-31 + masked in-place rewrite. One block (256 thr) per row.
// Row in REGISTERS (12 float4/thread); per-thread top-2 cache; unique owner
// per round; lazy rebuild via 48-bit dead mask. ONE barrier per round:
// double-buffered wave-top slots (redv[k&1]) remove the WAR barrier, and
// every thread redundantly combines the 4 wave-tops (no tid-0 funnel, no
// broadcast variable). Winners kept in registers (thread k holds winner k).
// ---------------------------------------------------------------------------
__device__ __forceinline__ void ins2(float val, int idx,
                                     float& v0, int& i0, float& v1, int& i1)
{
  const bool b0 = better(val, idx, v0, i0);
  const bool b1 = better(val, idx, v1, i1);
  const float nv1 = b0 ? v0 : (b1 ? val : v1);
  const int   ni1 = b0 ? i0 : (b1 ? idx : i1);
  v0 = b0 ? val : v0; i0 = b0 ? idx : i0;
  v1 = nv1; i1 = ni1;
}

__device__ __forceinline__ void rebuild2(const float4 (&v)[12], uint64_t dead,
                                         int tid, float& v0, int& i0,
                                         float& v1, int& i1)
{
  v0 = NEG_INF_F; i0 = IDX_MAX; v1 = NEG_INF_F; i1 = IDX_MAX;
#pragma unroll
  for (int i = 0; i < 12; ++i) {
    const int cbase = tid * 4 + i * 1024;
    float e;
    e = ((dead >> (i * 4 + 0)) & 1ull) ? NEG_INF_F : v[i].x;
    ins2(e, cbase + 0, v0, i0, v1, i1);
    e = ((dead >> (i * 4 + 1)) & 1ull) ? NEG_INF_F : v[i].y;
    ins2(e, cbase + 1, v0, i0, v1, i1);
    e = ((dead >> (i * 4 + 2)) & 1ull) ? NEG_INF_F : v[i].z;
    ins2(e, cbase + 2, v0, i0, v1, i1);
    e = ((dead >> (i * 4 + 3)) & 1ull) ? NEG_INF_F : v[i].w;
    ins2(e, cbase + 3, v0, i0, v1, i1);
  }
}

__global__ __launch_bounds__(256)
void topk_mask(float* __restrict__ S)
{
  __shared__ float redv[2][4];
  __shared__ int   redi[2][4];

  const int tid = threadIdx.x;
  const int row = blockIdx.x;
  float* Srow = S + (size_t)row * NROWS;

  float4 v[12];
#pragma unroll
  for (int i = 0; i < 12; ++i)
    v[i] = *(const float4*)(Srow + tid * 4 + i * 1024);

  uint64_t dead = 0;
  float v0, v1; int i0, i1;
  rebuild2(v, dead, tid, v0, i0, v1, i1);

  float mywv = 0.f; int mywi = -1;   // thread k holds winner k (k < TOPK)

  for (int k = 0; k < TOPK; ++k) {
    float bv = v0; int bi = i0;
#pragma unroll
    for (int o = 32; o > 0; o >>= 1) {
      const float ov = __shfl_down(bv, o);
      const int oi = __shfl_down(bi, o);
      if (better(ov, oi, bv, bi)) { bv = ov; bi = oi; }
    }
    if ((tid & 63) == 0) { redv[k & 1][tid >> 6] = bv; redi[k & 1][tid >> 6] = bi; }
    __syncthreads();
    float fbv = redv[k & 1][0]; int fbi = redi[k & 1][0];
#pragma unroll
    for (int w = 1; w < 4; ++w)
      if (better(redv[k & 1][w], redi[k & 1][w], fbv, fbi)) {
        fbv = redv[k & 1][w]; fbi = redi[k & 1][w];
      }
    if (tid == k) { mywv = fbv; mywi = fbi; }
    if (i0 == fbi) {                     // unique owner: update cache
      const int slot = ((fbi >> 10) << 2) | (fbi & 3);
      dead |= (1ull << slot);
      v0 = v1; i0 = i1;
      v1 = NEG_INF_F; i1 = IDX_MAX;
      if (i0 == IDX_MAX) rebuild2(v, dead, tid, v0, i0, v1, i1);
    }
  }

  const float4 z = {0.f, 0.f, 0.f, 0.f};
#pragma unroll
  for (int i = 0; i < 12; ++i)
    *(float4*)(Srow + tid * 4 + i * 1024) = z;
  __syncthreads();  // order zero-stores before winner scatter
  if (tid < TOPK) Srow[mywi] = fmaxf(mywv, 0.f);
}

// ---------------------------------------------------------------------------
extern "C" void kernel_launch(void* const* d_in, const int* in_sizes, int n_in,
                              void* d_out, int out_size, void* d_ws, size_t ws_size,
                              hipStream_t stream)
{
  const float* feat = (const float*)d_in[0];
  const float* W1 = (const float*)d_in[1];
  const float* b1 = (const float*)d_in[2];
  const float* W2 = (const float*)d_in[3];
  const float* b2 = (const float*)d_in[4];
  const float* W3 = (const float*)d_in[5];
  const float* b3 = (const float*)d_in[6];
  float* S = (float*)d_out;   // full sim matrix in d_out, masked in place

  // d_ws (62.9 MB): X1, X2, E
  float* X1 = (float*)d_ws;                          // 25.2 MB
  float* X2 = X1 + (size_t)NROWS * HDIM;             // 25.2 MB
  float* E  = X2 + (size_t)NROWS * HDIM;             // 12.6 MB

  gemm_nt_serial<true><<<dim3(HDIM / 64, NROWS / 64), 256, 0, stream>>>(
      feat, W1, b1, X1, HDIM, FDIM);
  gemm_nt_serial<true><<<dim3(HDIM / 64, NROWS / 64), 256, 0, stream>>>(
      X1, W2, b2, X2, HDIM, HDIM);
  gemm_nt_serial<false><<<dim3(ODIM / 64, NROWS / 64), 256, 0, stream>>>(
      X2, W3, b3, E, ODIM, HDIM);
  l2norm_np<<<NROWS / 256, 256, 0, stream>>>(E);
  sim_gemm<<<dim3(NROWS / 128, NROWS / 128), 256, 0, stream>>>(E, S);
  topk_mask<<<NROWS, 256, 0, stream>>>(S);
}

// Round 13
// 1485.177 us; speedup vs baseline: 7.9781x; 1.1799x over previous
//
#include <hip/hip_runtime.h>
#include <cstdint>
#include <cstddef>

#define NROWS 12288
#define FDIM 768
#define HDIM 512
#define ODIM 256
#define TOPK 31                // knn_k + 1

#define NEG_INF_F (-__builtin_inff())
#define IDX_MAX 0x7fffffff

__device__ __forceinline__ bool better(float v, int i, float v2, int i2)
{
  return (v > v2) || (v == v2 && i < i2);
}

// ---------------------------------------------------------------------------
// 64-tile fp32 GEMM (OpenBLAS-bitwise: serial ascending-k FMA chains, fold
// at K/2), swizzled LDS k-rows (conflict-free). Used for layer 3 (small N).
// ---------------------------------------------------------------------------
template<bool RELU>
__global__ __launch_bounds__(256)
void gemm_nt_serial(const float* __restrict__ A, const float* __restrict__ B,
                    const float* __restrict__ bias, float* __restrict__ C,
                    int Nout, int K)
{
  __shared__ float As[32][68];
  __shared__ float Bs[32][68];
  const int tid = threadIdx.x;
  const int tx = tid & 15, ty = tid >> 4;
  const int r0 = blockIdx.y * 64, c0 = blockIdx.x * 64;
  float acc[4][4] = {};
  float accC[4][4];
  bool first = true;
  const int Khalf = K / 2;

  for (int k0 = 0; k0 < K; k0 += 32) {
#pragma unroll
    for (int l = 0; l < 2; ++l) {
      const int lin = l * 256 + tid;
      const int row = lin >> 3, kq = lin & 7;
      const float4 a = *(const float4*)(A + (size_t)(r0 + row) * K + k0 + kq * 4);
      As[kq + 0][row] = a.x; As[kq + 8][row] = a.y;
      As[kq + 16][row] = a.z; As[kq + 24][row] = a.w;
      const float4 b = *(const float4*)(B + (size_t)(c0 + row) * K + k0 + kq * 4);
      Bs[kq + 0][row] = b.x; Bs[kq + 8][row] = b.y;
      Bs[kq + 16][row] = b.z; Bs[kq + 24][row] = b.w;
    }
    __syncthreads();
#pragma unroll
    for (int kk = 0; kk < 32; ++kk) {
      const int kp = ((kk & 3) << 3) | (kk >> 2);
      const float4 av = *(const float4*)&As[kp][ty * 4];
      const float4 bv = *(const float4*)&Bs[kp][tx * 4];
      const float a4[4] = {av.x, av.y, av.z, av.w};
      const float b4[4] = {bv.x, bv.y, bv.z, bv.w};
#pragma unroll
      for (int i = 0; i < 4; ++i)
#pragma unroll
        for (int j = 0; j < 4; ++j)
          acc[i][j] = fmaf(a4[i], b4[j], acc[i][j]);
    }
    __syncthreads();

    if ((k0 + 32 == Khalf) || (k0 + 32 == K)) {
#pragma unroll
      for (int i = 0; i < 4; ++i)
#pragma unroll
        for (int j = 0; j < 4; ++j) {
          accC[i][j] = first ? acc[i][j] : __fadd_rn(accC[i][j], acc[i][j]);
          acc[i][j] = 0.f;
        }
      first = false;
    }
  }

  const float4 bq = *(const float4*)(bias + c0 + tx * 4);
  const float bb[4] = {bq.x, bq.y, bq.z, bq.w};
#pragma unroll
  for (int i = 0; i < 4; ++i) {
    float v[4];
#pragma unroll
    for (int j = 0; j < 4; ++j) {
      v[j] = __fadd_rn(accC[i][j], bb[j]);
      if (RELU) v[j] = fmaxf(v[j], 0.f);
    }
    float4 o; o.x = v[0]; o.y = v[1]; o.z = v[2]; o.w = v[3];
    *(float4*)(C + (size_t)(r0 + ty * 4 + i) * Nout + c0 + tx * 4) = o;
  }
}

// ---------------------------------------------------------------------------
// 128-tile fp32 GEMM, 8x8 micro (split cols tx*4 / 64+tx*4), swizzled LDS,
// OpenBLAS-bitwise fold at K/2. Used for layers 1 and 2.
// ---------------------------------------------------------------------------
template<bool RELU>
__global__ __launch_bounds__(256)
void gemm_big_nt(const float* __restrict__ A, const float* __restrict__ B,
                 const float* __restrict__ bias, float* __restrict__ C,
                 int Nout, int K)
{
  __shared__ float As[32][132];
  __shared__ float Bs[32][132];
  const int tid = threadIdx.x;
  const int tx = tid & 15, ty = tid >> 4;
  const int r0 = blockIdx.y * 128, c0 = blockIdx.x * 128;
  float acc[8][8] = {};
  float accC[8][8];
  bool first = true;
  const int Khalf = K / 2;

  for (int k0 = 0; k0 < K; k0 += 32) {
#pragma unroll
    for (int l = 0; l < 4; ++l) {
      const int lin = l * 256 + tid;
      const int row = lin >> 3, q = lin & 7;
      const float4 a = *(const float4*)(A + (size_t)(r0 + row) * K + k0 + q * 4);
      As[q + 0][row] = a.x; As[q + 8][row] = a.y;
      As[q + 16][row] = a.z; As[q + 24][row] = a.w;
      const float4 b = *(const float4*)(B + (size_t)(c0 + row) * K + k0 + q * 4);
      Bs[q + 0][row] = b.x; Bs[q + 8][row] = b.y;
      Bs[q + 16][row] = b.z; Bs[q + 24][row] = b.w;
    }
    __syncthreads();
#pragma unroll
    for (int kk = 0; kk < 32; ++kk) {
      const int kp = ((kk & 3) << 3) | (kk >> 2);
      float a8[8], b8[8];
      *(float4*)&a8[0] = *(const float4*)&As[kp][ty * 8];
      *(float4*)&a8[4] = *(const float4*)&As[kp][ty * 8 + 4];
      *(float4*)&b8[0] = *(const float4*)&Bs[kp][tx * 4];
      *(float4*)&b8[4] = *(const float4*)&Bs[kp][64 + tx * 4];
#pragma unroll
      for (int i = 0; i < 8; ++i)
#pragma unroll
        for (int j = 0; j < 8; ++j)
          acc[i][j] = fmaf(a8[i], b8[j], acc[i][j]);
    }
    __syncthreads();

    if ((k0 + 32 == Khalf) || (k0 + 32 == K)) {
#pragma unroll
      for (int i = 0; i < 8; ++i)
#pragma unroll
        for (int j = 0; j < 8; ++j) {
          accC[i][j] = first ? acc[i][j] : __fadd_rn(accC[i][j], acc[i][j]);
          acc[i][j] = 0.f;
        }
      first = false;
    }
  }

  const float4 bq0 = *(const float4*)(bias + c0 + tx * 4);
  const float4 bq1 = *(const float4*)(bias + c0 + 64 + tx * 4);
  const float bb[8] = {bq0.x, bq0.y, bq0.z, bq0.w, bq1.x, bq1.y, bq1.z, bq1.w};
#pragma unroll
  for (int i = 0; i < 8; ++i) {
    float v[8];
#pragma unroll
    for (int j = 0; j < 8; ++j) {
      v[j] = __fadd_rn(accC[i][j], bb[j]);
      if (RELU) v[j] = fmaxf(v[j], 0.f);
    }
    float* dst = C + (size_t)(r0 + ty * 8 + i) * Nout + c0;
    float4 o0; o0.x = v[0]; o0.y = v[1]; o0.z = v[2]; o0.w = v[3];
    float4 o1; o1.x = v[4]; o1.y = v[5]; o1.z = v[6]; o1.w = v[7];
    *(float4*)(dst + tx * 4) = o0;
    *(float4*)(dst + 64 + tx * 4) = o1;
  }
}

// ---------------------------------------------------------------------------
// Row L2-normalize replicating numpy pairwise_sum bitwise (n=256) + IEEE
// sqrt/divide. One thread per row.
// ---------------------------------------------------------------------------
__global__ __launch_bounds__(256)
void l2norm_np(float* __restrict__ X)
{
  const int row = blockIdx.x * 256 + threadIdx.x;
  float* x = X + (size_t)row * ODIM;

  float S = 0.f;
#pragma unroll
  for (int h = 0; h < 2; ++h) {
    const float* a = x + h * 128;
    float r0 = __fmul_rn(a[0], a[0]);
    float r1 = __fmul_rn(a[1], a[1]);
    float r2 = __fmul_rn(a[2], a[2]);
    float r3 = __fmul_rn(a[3], a[3]);
    float r4 = __fmul_rn(a[4], a[4]);
    float r5 = __fmul_rn(a[5], a[5]);
    float r6 = __fmul_rn(a[6], a[6]);
    float r7 = __fmul_rn(a[7], a[7]);
    for (int i = 8; i < 128; i += 8) {
      r0 = __fadd_rn(r0, __fmul_rn(a[i + 0], a[i + 0]));
      r1 = __fadd_rn(r1, __fmul_rn(a[i + 1], a[i + 1]));
      r2 = __fadd_rn(r2, __fmul_rn(a[i + 2], a[i + 2]));
      r3 = __fadd_rn(r3, __fmul_rn(a[i + 3], a[i + 3]));
      r4 = __fadd_rn(r4, __fmul_rn(a[i + 4], a[i + 4]));
      r5 = __fadd_rn(r5, __fmul_rn(a[i + 5], a[i + 5]));
      r6 = __fadd_rn(r6, __fmul_rn(a[i + 6], a[i + 6]));
      r7 = __fadd_rn(r7, __fmul_rn(a[i + 7], a[i + 7]));
    }
    const float half = __fadd_rn(
        __fadd_rn(__fadd_rn(r0, r1), __fadd_rn(r2, r3)),
        __fadd_rn(__fadd_rn(r4, r5), __fadd_rn(r6, r7)));
    S = (h == 0) ? half : __fadd_rn(S, half);
  }

  const float d = fmaxf(__fsqrt_rn(S), 1e-12f);
  for (int k = 0; k < ODIM; ++k) x[k] = __fdiv_rn(x[k], d);
}

// ---------------------------------------------------------------------------
// SYMMETRIC fp32 sim GEMM: S = E @ E^T. Upper-triangle blocks only
// (bx >= by); off-diagonal tiles are mirrored to S^T via an LDS transpose.
// Bitwise-safe: fmaf(a,b,c) == fmaf(b,a,c), so S[j][i]'s serial-k chain is
// bit-identical to S[i][j]'s. Single serial ascending-k chain (K=256 <= Q).
// 128x128 tile, 8x8 micro (split cols), swizzled LDS k-rows.
// ---------------------------------------------------------------------------
__global__ __launch_bounds__(256)
void sim_gemm_sym(const float* __restrict__ E, float* __restrict__ S)
{
  __shared__ float lds[8448];                 // As | Bs, reused as Ts
  float (*As)[132] = (float(*)[132])lds;
  float (*Bs)[132] = (float(*)[132])(lds + 4224);
  const int tid = threadIdx.x;
  const int bx = blockIdx.x, by = blockIdx.y;
  if (bx < by) return;                        // uniform exit: lower triangle
  const int tx = tid & 15, ty = tid >> 4;
  const int r0 = by * 128, c0 = bx * 128;
  float acc[8][8] = {};

#pragma unroll
  for (int k0 = 0; k0 < ODIM; k0 += 32) {
#pragma unroll
    for (int l = 0; l < 4; ++l) {
      const int lin = l * 256 + tid;
      const int row = lin >> 3, q = lin & 7;
      const float4 a = *(const float4*)(E + (size_t)(r0 + row) * ODIM + k0 + q * 4);
      As[q + 0][row] = a.x; As[q + 8][row] = a.y;
      As[q + 16][row] = a.z; As[q + 24][row] = a.w;
      const float4 b = *(const float4*)(E + (size_t)(c0 + row) * ODIM + k0 + q * 4);
      Bs[q + 0][row] = b.x; Bs[q + 8][row] = b.y;
      Bs[q + 16][row] = b.z; Bs[q + 24][row] = b.w;
    }
    __syncthreads();
#pragma unroll
    for (int kk = 0; kk < 32; ++kk) {
      const int kp = ((kk & 3) << 3) | (kk >> 2);
      float a8[8], b8[8];
      *(float4*)&a8[0] = *(const float4*)&As[kp][ty * 8];
      *(float4*)&a8[4] = *(const float4*)&As[kp][ty * 8 + 4];
      *(float4*)&b8[0] = *(const float4*)&Bs[kp][tx * 4];
      *(float4*)&b8[4] = *(const float4*)&Bs[kp][64 + tx * 4];
#pragma unroll
      for (int i = 0; i < 8; ++i)
#pragma unroll
        for (int j = 0; j < 8; ++j)
          acc[i][j] = fmaf(a8[i], b8[j], acc[i][j]);
    }
    __syncthreads();
  }

  // direct write of tile (rows r0.., cols c0..)
#pragma unroll
  for (int i = 0; i < 8; ++i) {
    float4 o0, o1;
    o0.x = acc[i][0]; o0.y = acc[i][1]; o0.z = acc[i][2]; o0.w = acc[i][3];
    o1.x = acc[i][4]; o1.y = acc[i][5]; o1.z = acc[i][6]; o1.w = acc[i][7];
    float* dst = S + (size_t)(r0 + ty * 8 + i) * NROWS + c0;
    *(float4*)(dst + tx * 4) = o0;
    *(float4*)(dst + 64 + tx * 4) = o1;
  }

  if (bx == by) return;

  // mirrored write of tile^T (rows c0.., cols r0..) via LDS, two 64-col halves
  for (int h = 0; h < 2; ++h) {
    __syncthreads();                          // Ts free (prev half consumed)
    if ((ty >> 3) == h) {                     // waves 2h,2h+1 fill
      const int rr = (ty & 7) * 8;            // + i
#pragma unroll
      for (int i = 0; i < 8; ++i)
#pragma unroll
        for (int j = 0; j < 4; ++j) {
          lds[(size_t)(tx * 4 + j) * 65 + rr + i] = acc[i][j];
          lds[(size_t)(64 + tx * 4 + j) * 65 + rr + i] = acc[i][4 + j];
        }
    }
    __syncthreads();
    const int rt = tid >> 1;                  // mirrored row within tile
    const int cb = (tid & 1) * 32;            // col base within half
#pragma unroll
    for (int q = 0; q < 8; ++q) {
      float4 val;
      val.x = lds[(size_t)rt * 65 + cb + q * 4 + 0];
      val.y = lds[(size_t)rt * 65 + cb + q * 4 + 1];
      val.z = lds[(size_t)rt * 65 + cb + q * 4 + 2];
      val.w = lds[(size_t)rt * 65 + cb + q * 4 + 3];
      *(float4*)(S + (size_t)(c0 + rt) * NROWS + r0 + 64 * h + cb + q * 4) = val;
    }
  }
}

// ---------------------------------------------------------------------------
// Per-row exact top-31 + masked in-place rewrite. One block (256 thr) per row.
// Row in REGISTERS; per-thread top-2 cache; unique owner per round; lazy
// rebuild via 48-bit dead mask; one barrier per round (double-buffered
// wave-top slots, redundant combine). Winners in registers.
// ---------------------------------------------------------------------------
__device__ __forceinline__ void ins2(float val, int idx,
                                     float& v0, int& i0, float& v1, int& i1)
{
  const bool b0 = better(val, idx, v0, i0);
  const bool b1 = better(val, idx, v1, i1);
  const float nv1 = b0 ? v0 : (b1 ? val : v1);
  const int   ni1 = b0 ? i0 : (b1 ? idx : i1);
  v0 = b0 ? val : v0; i0 = b0 ? idx : i0;
  v1 = nv1; i1 = ni1;
}

__device__ __forceinline__ void rebuild2(const float4 (&v)[12], uint64_t dead,
                                         int tid, float& v0, int& i0,
                                         float& v1, int& i1)
{
  v0 = NEG_INF_F; i0 = IDX_MAX; v1 = NEG_INF_F; i1 = IDX_MAX;
#pragma unroll
  for (int i = 0; i < 12; ++i) {
    const int cbase = tid * 4 + i * 1024;
    float e;
    e = ((dead >> (i * 4 + 0)) & 1ull) ? NEG_INF_F : v[i].x;
    ins2(e, cbase + 0, v0, i0, v1, i1);
    e = ((dead >> (i * 4 + 1)) & 1ull) ? NEG_INF_F : v[i].y;
    ins2(e, cbase + 1, v0, i0, v1, i1);
    e = ((dead >> (i * 4 + 2)) & 1ull) ? NEG_INF_F : v[i].z;
    ins2(e, cbase + 2, v0, i0, v1, i1);
    e = ((dead >> (i * 4 + 3)) & 1ull) ? NEG_INF_F : v[i].w;
    ins2(e, cbase + 3, v0, i0, v1, i1);
  }
}

__global__ __launch_bounds__(256)
void topk_mask(float* __restrict__ S)
{
  __shared__ float redv[2][4];
  __shared__ int   redi[2][4];

  const int tid = threadIdx.x;
  const int row = blockIdx.x;
  float* Srow = S + (size_t)row * NROWS;

  float4 v[12];
#pragma unroll
  for (int i = 0; i < 12; ++i)
    v[i] = *(const float4*)(Srow + tid * 4 + i * 1024);

  uint64_t dead = 0;
  float v0, v1; int i0, i1;
  rebuild2(v, dead, tid, v0, i0, v1, i1);

  float mywv = 0.f; int mywi = -1;

  for (int k = 0; k < TOPK; ++k) {
    float bv = v0; int bi = i0;
#pragma unroll
    for (int o = 32; o > 0; o >>= 1) {
      const float ov = __shfl_down(bv, o);
      const int oi = __shfl_down(bi, o);
      if (better(ov, oi, bv, bi)) { bv = ov; bi = oi; }
    }
    if ((tid & 63) == 0) { redv[k & 1][tid >> 6] = bv; redi[k & 1][tid >> 6] = bi; }
    __syncthreads();
    float fbv = redv[k & 1][0]; int fbi = redi[k & 1][0];
#pragma unroll
    for (int w = 1; w < 4; ++w)
      if (better(redv[k & 1][w], redi[k & 1][w], fbv, fbi)) {
        fbv = redv[k & 1][w]; fbi = redi[k & 1][w];
      }
    if (tid == k) { mywv = fbv; mywi = fbi; }
    if (i0 == fbi) {
      const int slot = ((fbi >> 10) << 2) | (fbi & 3);
      dead |= (1ull << slot);
      v0 = v1; i0 = i1;
      v1 = NEG_INF_F; i1 = IDX_MAX;
      if (i0 == IDX_MAX) rebuild2(v, dead, tid, v0, i0, v1, i1);
    }
  }

  const float4 z = {0.f, 0.f, 0.f, 0.f};
#pragma unroll
  for (int i = 0; i < 12; ++i)
    *(float4*)(Srow + tid * 4 + i * 1024) = z;
  __syncthreads();
  if (tid < TOPK) Srow[mywi] = fmaxf(mywv, 0.f);
}

// ---------------------------------------------------------------------------
extern "C" void kernel_launch(void* const* d_in, const int* in_sizes, int n_in,
                              void* d_out, int out_size, void* d_ws, size_t ws_size,
                              hipStream_t stream)
{
  const float* feat = (const float*)d_in[0];
  const float* W1 = (const float*)d_in[1];
  const float* b1 = (const float*)d_in[2];
  const float* W2 = (const float*)d_in[3];
  const float* b2 = (const float*)d_in[4];
  const float* W3 = (const float*)d_in[5];
  const float* b3 = (const float*)d_in[6];
  float* S = (float*)d_out;   // full sim matrix in d_out, masked in place

  // d_ws (62.9 MB): X1, X2, E
  float* X1 = (float*)d_ws;                          // 25.2 MB
  float* X2 = X1 + (size_t)NROWS * HDIM;             // 25.2 MB
  float* E  = X2 + (size_t)NROWS * HDIM;             // 12.6 MB

  gemm_big_nt<true><<<dim3(HDIM / 128, NROWS / 128), 256, 0, stream>>>(
      feat, W1, b1, X1, HDIM, FDIM);
  gemm_big_nt<true><<<dim3(HDIM / 128, NROWS / 128), 256, 0, stream>>>(
      X1, W2, b2, X2, HDIM, HDIM);
  gemm_nt_serial<false><<<dim3(ODIM / 64, NROWS / 64), 256, 0, stream>>>(
      X2, W3, b3, E, ODIM, HDIM);
  l2norm_np<<<NROWS / 256, 256, 0, stream>>>(E);
  sim_gemm_sym<<<dim3(NROWS / 128, NROWS / 128), 256, 0, stream>>>(E, S);
  topk_mask<<<NROWS, 256, 0, stream>>>(S);
}